// Round 1
// baseline (1637.603 us; speedup 1.0000x reference)
//
#include <hip/hip_runtime.h>
#include <math.h>

#define NN 20000
#define NE 640000
#define HDIM 128
#define GDIM 50
#define LAYERS 6
#define NGRAPH 64
#define TBL 2048
#define DMAXF 12.8f

__device__ __forceinline__ float sspf(float x) {
    float sp = (x > 30.0f) ? x : log1pf(expf(x));
    return sp - 0.69314718055994530942f;
}

__global__ void zero_i32(int* p, int n) {
    int i = blockIdx.x * blockDim.x + threadIdx.x;
    if (i < n) p[i] = 0;
}

// per-edge distance, cosine cutoff, and dst-degree histogram
__global__ void edge_geom(const float* __restrict__ pos, const int* __restrict__ src,
                          const int* __restrict__ dst, float* __restrict__ d_e,
                          float* __restrict__ c_e, int* __restrict__ deg) {
    int j = blockIdx.x * blockDim.x + threadIdx.x;
    if (j >= NE) return;
    int s = src[j], t = dst[j];
    float dx = pos[3*s+0] - pos[3*t+0];
    float dy = pos[3*s+1] - pos[3*t+1];
    float dz = pos[3*s+2] - pos[3*t+2];
    float d = sqrtf(dx*dx + dy*dy + dz*dz);
    d_e[j] = d;
    c_e[j] = 0.5f * (cosf(d * 0.31415926535897931f) + 1.0f);
    atomicAdd(&deg[t], 1);
}

// single-block exclusive scan of deg -> row_ptr[0..NN], cursor[0..NN-1]
__global__ void scan_deg(const int* __restrict__ deg, int* __restrict__ row_ptr,
                         int* __restrict__ cursor) {
    __shared__ int part[1024];
    const int n = NN;
    const int PER = 20; // 1024*20 >= NN+1
    int t = threadIdx.x;
    int base = t * PER;
    int local[PER];
    int s = 0;
    #pragma unroll
    for (int i = 0; i < PER; i++) {
        int k = base + i;
        local[i] = s;
        if (k < n) s += deg[k];
    }
    part[t] = s;
    __syncthreads();
    for (int off = 1; off < 1024; off <<= 1) {
        int v = (t >= off) ? part[t - off] : 0;
        __syncthreads();
        part[t] += v;
        __syncthreads();
    }
    int offset = (t > 0) ? part[t - 1] : 0;
    #pragma unroll
    for (int i = 0; i < PER; i++) {
        int k = base + i;
        if (k <= n) {
            int v = offset + local[i];
            row_ptr[k] = v;
            if (k < n) cursor[k] = v;
        }
    }
}

__global__ void csr_fill(const int* __restrict__ src, const int* __restrict__ dst,
                         const float* __restrict__ d_e, const float* __restrict__ c_e,
                         int* __restrict__ cursor, int* __restrict__ csr_src,
                         float* __restrict__ csr_d, float* __restrict__ csr_c) {
    int j = blockIdx.x * blockDim.x + threadIdx.x;
    if (j >= NE) return;
    int t = dst[j];
    int p = atomicAdd(&cursor[t], 1);
    csr_src[p] = src[j];
    csr_d[p] = d_e[j];
    csr_c[p] = c_e[j];
}

// gaussian smearing rows for table samples; last row = zeros (d >= DMAX regime)
__global__ void attr_table(float* __restrict__ A) {
    int idx = blockIdx.x * blockDim.x + threadIdx.x;
    const int total = (TBL + 2) * GDIM;
    if (idx >= total) return;
    int i = idx / GDIM, g = idx % GDIM;
    float v = 0.0f;
    if (i <= TBL) {
        float d = (float)i * (DMAXF / (float)TBL);
        float step = 10.0f / 49.0f;
        float off = (float)g * step;
        float coeff = -0.5f / (step * step);
        float dd = d - off;
        v = expf(coeff * dd * dd);
    }
    A[idx] = v;
}

// Y[M,128] = act(A[M,K] @ W[K,128] + bias) + resid   (bias/resid nullable)
template <int K>
__launch_bounds__(256, 2)
__global__ void gemm_t(const float* __restrict__ A, const float* __restrict__ W,
                       const float* __restrict__ bias, const float* __restrict__ resid,
                       float* __restrict__ Y, int M, int act) {
    __shared__ __align__(16) float Ws[128 * 128];
    __shared__ __align__(16) float As[32 * 128];
    int t = threadIdx.x;
    int row0 = blockIdx.x * 32;
    for (int i = t; i < K * 128; i += 256) Ws[i] = W[i];
    const float* Atile = A + (size_t)row0 * K;
    int avail = (M - row0) * K;
    for (int i = t; i < 32 * K; i += 256) As[i] = (i < avail) ? Atile[i] : 0.0f;
    __syncthreads();
    int tx = t & 31, ty = t >> 5;
    int c0 = tx * 4, r0 = ty * 4;
    float acc[4][4] = {{0.f}};
    #pragma unroll 4
    for (int k = 0; k < K; k++) {
        float4 wv = *(const float4*)&Ws[k * 128 + c0];
        float a0 = As[(r0 + 0) * K + k];
        float a1 = As[(r0 + 1) * K + k];
        float a2 = As[(r0 + 2) * K + k];
        float a3 = As[(r0 + 3) * K + k];
        acc[0][0] += a0 * wv.x; acc[0][1] += a0 * wv.y; acc[0][2] += a0 * wv.z; acc[0][3] += a0 * wv.w;
        acc[1][0] += a1 * wv.x; acc[1][1] += a1 * wv.y; acc[1][2] += a1 * wv.z; acc[1][3] += a1 * wv.w;
        acc[2][0] += a2 * wv.x; acc[2][1] += a2 * wv.y; acc[2][2] += a2 * wv.z; acc[2][3] += a2 * wv.w;
        acc[3][0] += a3 * wv.x; acc[3][1] += a3 * wv.y; acc[3][2] += a3 * wv.z; acc[3][3] += a3 * wv.w;
    }
    float b0 = 0.f, b1 = 0.f, b2 = 0.f, b3 = 0.f;
    if (bias) { b0 = bias[c0]; b1 = bias[c0+1]; b2 = bias[c0+2]; b3 = bias[c0+3]; }
    #pragma unroll
    for (int i = 0; i < 4; i++) {
        int r = row0 + r0 + i;
        if (r >= M) break;
        float4 v;
        v.x = acc[i][0] + b0; v.y = acc[i][1] + b1; v.z = acc[i][2] + b2; v.w = acc[i][3] + b3;
        if (act == 1) { v.x = sspf(v.x); v.y = sspf(v.y); v.z = sspf(v.z); v.w = sspf(v.w); }
        if (resid) {
            float4 rv = *(const float4*)&resid[(size_t)r * 128 + c0];
            v.x += rv.x; v.y += rv.y; v.z += rv.z; v.w += rv.w;
        }
        *(float4*)&Y[(size_t)r * 128 + c0] = v;
    }
}

__global__ void h_init(const int* __restrict__ z, const float* __restrict__ emb,
                       float* __restrict__ h) {
    int idx = blockIdx.x * blockDim.x + threadIdx.x;
    if (idx >= NN * 32) return;
    int n = idx >> 5, q = idx & 31;
    ((float4*)h)[n * 32 + q] = ((const float4*)emb)[z[n] * 32 + q];
}

// one wave per node: agg[n] = sum_{e in CSR(n)} xf[src_e] * lerp(T, d_e) * C_e
__launch_bounds__(256)
__global__ void edge_agg(const int* __restrict__ row_ptr, const int* __restrict__ csr_src,
                         const float* __restrict__ csr_d, const float* __restrict__ csr_c,
                         const float* __restrict__ T, const float* __restrict__ xf,
                         float* __restrict__ agg) {
    int wave = threadIdx.x >> 6;
    int lane = threadIdx.x & 63;
    int n = blockIdx.x * 4 + wave;
    if (n >= NN) return;
    int e0 = row_ptr[n], e1 = row_ptr[n + 1];
    const float2* T2 = (const float2*)T;
    const float2* xf2 = (const float2*)xf;
    float ax = 0.f, ay = 0.f;
    for (int e = e0; e < e1; e++) {
        int s = csr_src[e];
        float dd = csr_d[e];
        float Cc = csr_c[e];
        float u = dd * ((float)TBL / DMAXF);
        float wx, wy;
        if (u >= (float)TBL) {
            float2 wf = T2[(TBL + 1) * 64 + lane];
            wx = wf.x; wy = wf.y;
        } else {
            int i0 = (int)u;
            float f = u - (float)i0;
            float2 w0 = T2[i0 * 64 + lane];
            float2 w1 = T2[(i0 + 1) * 64 + lane];
            wx = w0.x + f * (w1.x - w0.x);
            wy = w0.y + f * (w1.y - w0.y);
        }
        float2 xv = xf2[(size_t)s * 64 + lane];
        ax += xv.x * wx * Cc;
        ay += xv.y * wy * Cc;
    }
    float2 r; r.x = ax; r.y = ay;
    ((float2*)agg)[(size_t)n * 64 + lane] = r;
}

// mean over each graph's node range (batch sorted)
__global__ void readout(const float* __restrict__ hout, const int* __restrict__ batch,
                        float* __restrict__ out) {
    int g = blockIdx.x;
    int c = threadIdx.x; // 128
    __shared__ int sh[2];
    if (c < 2) {
        int target = g + c;
        int lo = 0, hi = NN;
        while (lo < hi) {
            int mid = (lo + hi) >> 1;
            if (batch[mid] < target) lo = mid + 1; else hi = mid;
        }
        sh[c] = lo;
    }
    __syncthreads();
    int lo = sh[0], hi = sh[1];
    float s = 0.f;
    for (int n = lo; n < hi; n++) s += hout[(size_t)n * 128 + c];
    int cnt = hi - lo;
    out[g * 128 + c] = s / (float)(cnt > 0 ? cnt : 1);
}

extern "C" void kernel_launch(void* const* d_in, const int* in_sizes, int n_in,
                              void* d_out, int out_size, void* d_ws, size_t ws_size,
                              hipStream_t stream) {
    const int*   z       = (const int*)d_in[0];
    const float* pos     = (const float*)d_in[1];
    const int*   eidx    = (const int*)d_in[2];
    const int*   src     = eidx;
    const int*   dst     = eidx + NE;
    const int*   batch   = (const int*)d_in[3];
    const float* emb     = (const float*)d_in[4];
    const float* mlp_w1  = (const float*)d_in[5];
    const float* mlp_b1  = (const float*)d_in[6];
    const float* mlp_w2  = (const float*)d_in[7];
    const float* mlp_b2  = (const float*)d_in[8];
    const float* conv_w1 = (const float*)d_in[9];
    const float* conv_w2 = (const float*)d_in[10];
    const float* conv_b2 = (const float*)d_in[11];
    const float* lin_w   = (const float*)d_in[12];
    const float* lin_b   = (const float*)d_in[13];
    const float* out1_w  = (const float*)d_in[14];
    const float* out1_b  = (const float*)d_in[15];
    const float* out2_w  = (const float*)d_in[16];
    const float* out2_b  = (const float*)d_in[17];
    float* out = (float*)d_out;

    char* wp = (char*)d_ws;
    auto alloc = [&](size_t bytes) {
        char* p = wp;
        wp += (bytes + 255) & ~(size_t)255;
        return p;
    };
    float* d_e     = (float*)alloc(NE * 4);
    float* c_e     = (float*)alloc(NE * 4);
    int*   deg     = (int*)alloc(NN * 4);
    int*   row_ptr = (int*)alloc((NN + 1) * 4);
    int*   cursor  = (int*)alloc(NN * 4);
    int*   csr_src = (int*)alloc(NE * 4);
    float* csr_d   = (float*)alloc(NE * 4);
    float* csr_c   = (float*)alloc(NE * 4);
    float* A_tab   = (float*)alloc((size_t)(TBL + 2) * GDIM * 4);
    float* T1      = (float*)alloc((size_t)(TBL + 2) * 128 * 4);
    float* T       = (float*)alloc((size_t)LAYERS * (TBL + 2) * 128 * 4);
    float* h       = (float*)alloc((size_t)NN * 128 * 4);
    float* xf      = (float*)alloc((size_t)NN * 128 * 4);
    float* agg     = (float*)alloc((size_t)NN * 128 * 4);
    float* t1      = (float*)alloc((size_t)NN * 128 * 4);

    // graph structure + geometry
    zero_i32<<<(NN + 255) / 256, 256, 0, stream>>>(deg, NN);
    edge_geom<<<(NE + 255) / 256, 256, 0, stream>>>(pos, src, dst, d_e, c_e, deg);
    scan_deg<<<1, 1024, 0, stream>>>(deg, row_ptr, cursor);
    csr_fill<<<(NE + 255) / 256, 256, 0, stream>>>(src, dst, d_e, c_e, cursor,
                                                   csr_src, csr_d, csr_c);

    // filter tables: T[l] = ssp(A_tab @ w1 + b1) @ w2 + b2
    attr_table<<<(((TBL + 2) * GDIM) + 255) / 256, 256, 0, stream>>>(A_tab);
    const int Mt = TBL + 2;
    const int gt = (Mt + 31) / 32;
    for (int l = 0; l < LAYERS; l++) {
        gemm_t<GDIM><<<gt, 256, 0, stream>>>(A_tab, mlp_w1 + (size_t)l * GDIM * 128,
                                             mlp_b1 + l * 128, nullptr, T1, Mt, 1);
        gemm_t<128><<<gt, 256, 0, stream>>>(T1, mlp_w2 + (size_t)l * 128 * 128,
                                            mlp_b2 + l * 128, nullptr,
                                            T + (size_t)l * Mt * 128, Mt, 0);
    }

    // node embedding
    h_init<<<(NN * 32 + 255) / 256, 256, 0, stream>>>(z, emb, h);

    const int gn = (NN + 31) / 32;
    for (int l = 0; l < LAYERS; l++) {
        // xf = h @ conv_w1[l]
        gemm_t<128><<<gn, 256, 0, stream>>>(h, conv_w1 + (size_t)l * 128 * 128,
                                            nullptr, nullptr, xf, NN, 0);
        // agg[n] = sum over incoming edges
        edge_agg<<<(NN + 3) / 4, 256, 0, stream>>>(row_ptr, csr_src, csr_d, csr_c,
                                                   T + (size_t)l * Mt * 128, xf, agg);
        // t1 = ssp(agg @ conv_w2[l] + b2)
        gemm_t<128><<<gn, 256, 0, stream>>>(agg, conv_w2 + (size_t)l * 128 * 128,
                                            conv_b2 + l * 128, nullptr, t1, NN, 1);
        // h = h + t1 @ lin_w[l] + lin_b[l]
        gemm_t<128><<<gn, 256, 0, stream>>>(t1, lin_w + (size_t)l * 128 * 128,
                                            lin_b + l * 128, h, h, NN, 0);
    }

    // output head: t2 = ssp(h @ out1_w + b1) ; hout = t2 @ out2_w + b2
    gemm_t<128><<<gn, 256, 0, stream>>>(h, out1_w, out1_b, nullptr, xf, NN, 1);
    gemm_t<128><<<gn, 256, 0, stream>>>(xf, out2_w, out2_b, nullptr, agg, NN, 0);

    // per-graph mean
    readout<<<NGRAPH, 128, 0, stream>>>(agg, batch, out);
}

// Round 2
// 1279.263 us; speedup vs baseline: 1.2801x; 1.2801x over previous
//
#include <hip/hip_runtime.h>
#include <math.h>

#define NN 20000
#define NE 640000
#define GDIM 50
#define LAYERS 6
#define NGRAPH 64
#define TBL 2048
#define DMAXF 12.8f

__device__ __forceinline__ float sspf(float x) {
    float sp = (x > 30.0f) ? x : log1pf(expf(x));
    return sp - 0.69314718055994530942f;
}

__global__ void zero_i32(int* p, int n) {
    int i = blockIdx.x * blockDim.x + threadIdx.x;
    if (i < n) p[i] = 0;
}

// dst-degree histogram
__global__ void deg_hist(const int* __restrict__ dst, int* __restrict__ deg) {
    int j = blockIdx.x * blockDim.x + threadIdx.x;
    if (j >= NE) return;
    atomicAdd(&deg[dst[j]], 1);
}

// single-block exclusive scan of deg -> row_ptr[0..NN], cursor[0..NN-1]
__global__ void scan_deg(const int* __restrict__ deg, int* __restrict__ row_ptr,
                         int* __restrict__ cursor) {
    __shared__ int part[1024];
    const int n = NN;
    const int PER = 20; // 1024*20 >= NN+1
    int t = threadIdx.x;
    int base = t * PER;
    int local[PER];
    int s = 0;
    #pragma unroll
    for (int i = 0; i < PER; i++) {
        int k = base + i;
        local[i] = s;
        if (k < n) s += deg[k];
    }
    part[t] = s;
    __syncthreads();
    for (int off = 1; off < 1024; off <<= 1) {
        int v = (t >= off) ? part[t - off] : 0;
        __syncthreads();
        part[t] += v;
        __syncthreads();
    }
    int offset = (t > 0) ? part[t - 1] : 0;
    #pragma unroll
    for (int i = 0; i < PER; i++) {
        int k = base + i;
        if (k <= n) {
            int v = offset + local[i];
            row_ptr[k] = v;
            if (k < n) cursor[k] = v;
        }
    }
}

// build CSR with precomputed lerp-gather metadata:
// csr_si = (src*64, i0*64) [float2-unit offsets], csr_g = (C*(1-f), C*f)
__global__ void csr_fill(const float* __restrict__ pos, const int* __restrict__ src,
                         const int* __restrict__ dst, int* __restrict__ cursor,
                         int2* __restrict__ csr_si, float2* __restrict__ csr_g) {
    int j = blockIdx.x * blockDim.x + threadIdx.x;
    if (j >= NE) return;
    int s = src[j], tno = dst[j];
    float dx = pos[3*s+0] - pos[3*tno+0];
    float dy = pos[3*s+1] - pos[3*tno+1];
    float dz = pos[3*s+2] - pos[3*tno+2];
    float d = sqrtf(dx*dx + dy*dy + dz*dz);
    float C = 0.5f * (cosf(d * 0.31415926535897931f) + 1.0f);
    float u = d * ((float)TBL / DMAXF);
    u = fminf(u, (float)(TBL + 1));
    int i0 = (int)u; if (i0 > TBL) i0 = TBL;
    float f = u - (float)i0;
    int p = atomicAdd(&cursor[tno], 1);
    csr_si[p] = make_int2(s * 64, i0 * 64);
    csr_g[p] = make_float2(C * (1.0f - f), C * f);
}

// gaussian smearing rows for table samples; row TBL+1 = zeros (tail regime)
__global__ void attr_table(float* __restrict__ A) {
    int idx = blockIdx.x * blockDim.x + threadIdx.x;
    const int total = (TBL + 2) * GDIM;
    if (idx >= total) return;
    int i = idx / GDIM, g = idx % GDIM;
    float v = 0.0f;
    if (i <= TBL) {
        float d = (float)i * (DMAXF / (float)TBL);
        float step = 10.0f / 49.0f;
        float off = (float)g * step;
        float coeff = -0.5f / (step * step);
        float dd = d - off;
        v = expf(coeff * dd * dd);
    }
    A[idx] = v;
}

// Y[M,128] = act(A[M,K] @ W[K,128] + bias) + resid   (bias/resid nullable)
// gridDim.y batches over L with the given strides.
template <int K>
__launch_bounds__(256, 2)
__global__ void gemm_t(const float* __restrict__ A, const float* __restrict__ W,
                       const float* __restrict__ bias, const float* __restrict__ resid,
                       float* __restrict__ Y, int M, int act,
                       int aStride, int wStride, int bStride, int yStride) {
    constexpr int KP = (K + 3) & ~3;
    __shared__ __align__(16) float Ws[KP * 128];
    __shared__ __align__(16) float As[32 * KP];
    int l = blockIdx.y;
    A += (size_t)l * aStride;
    W += (size_t)l * wStride;
    if (bias) bias += (size_t)l * bStride;
    Y += (size_t)l * yStride;
    int t = threadIdx.x;
    int row0 = blockIdx.x * 32;
    // stage W[K,128] (zero-pad K -> KP)
    if (K == KP) {
        const float4* W4 = (const float4*)W;
        float4* Ws4 = (float4*)Ws;
        for (int i = t; i < KP * 32; i += 256) Ws4[i] = W4[i];
    } else {
        for (int i = t; i < KP * 128; i += 256) Ws[i] = (i < K * 128) ? W[i] : 0.0f;
    }
    // stage A tile [32, K] row-major (zero-pad rows >= M and k >= K)
    if (K == KP) {
        for (int i = t; i < 32 * (KP / 4); i += 256) {
            int r = i / (KP / 4), kq = i % (KP / 4);
            float4 v = make_float4(0.f, 0.f, 0.f, 0.f);
            if (row0 + r < M) v = *(const float4*)&A[(size_t)(row0 + r) * K + kq * 4];
            *(float4*)&As[r * KP + kq * 4] = v;
        }
    } else {
        for (int i = t; i < 32 * KP; i += 256) {
            int r = i / KP, k = i % KP;
            float v = 0.f;
            if (k < K && row0 + r < M) v = A[(size_t)(row0 + r) * K + k];
            As[r * KP + k] = v;
        }
    }
    __syncthreads();
    int tx = t & 31, ty = t >> 5;
    int c0 = tx * 4, r0 = ty * 4;
    float acc[4][4] = {{0.f}};
    #pragma unroll 4
    for (int k = 0; k < KP; k += 4) {
        float4 a0 = *(const float4*)&As[(r0 + 0) * KP + k];
        float4 a1 = *(const float4*)&As[(r0 + 1) * KP + k];
        float4 a2 = *(const float4*)&As[(r0 + 2) * KP + k];
        float4 a3 = *(const float4*)&As[(r0 + 3) * KP + k];
        float4 w0 = *(const float4*)&Ws[(k + 0) * 128 + c0];
        float4 w1 = *(const float4*)&Ws[(k + 1) * 128 + c0];
        float4 w2 = *(const float4*)&Ws[(k + 2) * 128 + c0];
        float4 w3 = *(const float4*)&Ws[(k + 3) * 128 + c0];
        float av[4][4] = {{a0.x,a0.y,a0.z,a0.w},{a1.x,a1.y,a1.z,a1.w},
                          {a2.x,a2.y,a2.z,a2.w},{a3.x,a3.y,a3.z,a3.w}};
        float wv[4][4] = {{w0.x,w0.y,w0.z,w0.w},{w1.x,w1.y,w1.z,w1.w},
                          {w2.x,w2.y,w2.z,w2.w},{w3.x,w3.y,w3.z,w3.w}};
        #pragma unroll
        for (int i = 0; i < 4; i++)
            #pragma unroll
            for (int j = 0; j < 4; j++)
                #pragma unroll
                for (int q = 0; q < 4; q++)
                    acc[i][j] += av[i][q] * wv[q][j];
    }
    float b0 = 0.f, b1 = 0.f, b2 = 0.f, b3 = 0.f;
    if (bias) { b0 = bias[c0]; b1 = bias[c0+1]; b2 = bias[c0+2]; b3 = bias[c0+3]; }
    #pragma unroll
    for (int i = 0; i < 4; i++) {
        int r = row0 + r0 + i;
        if (r >= M) break;
        float4 v;
        v.x = acc[i][0] + b0; v.y = acc[i][1] + b1; v.z = acc[i][2] + b2; v.w = acc[i][3] + b3;
        if (act == 1) { v.x = sspf(v.x); v.y = sspf(v.y); v.z = sspf(v.z); v.w = sspf(v.w); }
        if (resid) {
            float4 rv = *(const float4*)&resid[(size_t)r * 128 + c0];
            v.x += rv.x; v.y += rv.y; v.z += rv.z; v.w += rv.w;
        }
        *(float4*)&Y[(size_t)r * 128 + c0] = v;
    }
}

__global__ void h_init(const int* __restrict__ z, const float* __restrict__ emb,
                       float* __restrict__ h) {
    int idx = blockIdx.x * blockDim.x + threadIdx.x;
    if (idx >= NN * 32) return;
    int n = idx >> 5, q = idx & 31;
    ((float4*)h)[n * 32 + q] = ((const float4*)emb)[z[n] * 32 + q];
}

// one wave per node: agg[n] = sum_e xf[src_e] * (g0*T[i0] + g1*T[i0+1]); 4x unrolled
__launch_bounds__(256)
__global__ void edge_agg(const int* __restrict__ row_ptr, const int2* __restrict__ csr_si,
                         const float2* __restrict__ csr_g, const float* __restrict__ T,
                         const float* __restrict__ xf, float* __restrict__ agg) {
    int wave = threadIdx.x >> 6;
    int lane = threadIdx.x & 63;
    int n = blockIdx.x * 4 + wave;
    if (n >= NN) return;
    int e0 = row_ptr[n], e1 = row_ptr[n + 1];
    const float2* T2 = (const float2*)T;
    const float2* xf2 = (const float2*)xf;
    float ax = 0.f, ay = 0.f;
    int e = e0;
    for (; e + 4 <= e1; e += 4) {
        int2 si0 = csr_si[e+0]; int2 si1 = csr_si[e+1];
        int2 si2 = csr_si[e+2]; int2 si3 = csr_si[e+3];
        float2 g0 = csr_g[e+0]; float2 g1 = csr_g[e+1];
        float2 g2 = csr_g[e+2]; float2 g3 = csr_g[e+3];
        float2 ta0 = T2[si0.y + lane], tb0 = T2[si0.y + 64 + lane];
        float2 ta1 = T2[si1.y + lane], tb1 = T2[si1.y + 64 + lane];
        float2 ta2 = T2[si2.y + lane], tb2 = T2[si2.y + 64 + lane];
        float2 ta3 = T2[si3.y + lane], tb3 = T2[si3.y + 64 + lane];
        float2 x0 = xf2[si0.x + lane];
        float2 x1 = xf2[si1.x + lane];
        float2 x2 = xf2[si2.x + lane];
        float2 x3 = xf2[si3.x + lane];
        ax += x0.x * (g0.x*ta0.x + g0.y*tb0.x); ay += x0.y * (g0.x*ta0.y + g0.y*tb0.y);
        ax += x1.x * (g1.x*ta1.x + g1.y*tb1.x); ay += x1.y * (g1.x*ta1.y + g1.y*tb1.y);
        ax += x2.x * (g2.x*ta2.x + g2.y*tb2.x); ay += x2.y * (g2.x*ta2.y + g2.y*tb2.y);
        ax += x3.x * (g3.x*ta3.x + g3.y*tb3.x); ay += x3.y * (g3.x*ta3.y + g3.y*tb3.y);
    }
    for (; e < e1; e++) {
        int2 si = csr_si[e]; float2 g = csr_g[e];
        float2 ta = T2[si.y + lane], tb = T2[si.y + 64 + lane];
        float2 x = xf2[si.x + lane];
        ax += x.x * (g.x*ta.x + g.y*tb.x); ay += x.y * (g.x*ta.y + g.y*tb.y);
    }
    float2 r; r.x = ax; r.y = ay;
    ((float2*)agg)[(size_t)n * 64 + lane] = r;
}

// mean over each graph's node range (batch sorted)
__global__ void readout(const float* __restrict__ hout, const int* __restrict__ batch,
                        float* __restrict__ out) {
    int g = blockIdx.x;
    int c = threadIdx.x; // 128
    __shared__ int sh[2];
    if (c < 2) {
        int target = g + c;
        int lo = 0, hi = NN;
        while (lo < hi) {
            int mid = (lo + hi) >> 1;
            if (batch[mid] < target) lo = mid + 1; else hi = mid;
        }
        sh[c] = lo;
    }
    __syncthreads();
    int lo = sh[0], hi = sh[1];
    float s = 0.f;
    for (int n = lo; n < hi; n++) s += hout[(size_t)n * 128 + c];
    int cnt = hi - lo;
    out[g * 128 + c] = s / (float)(cnt > 0 ? cnt : 1);
}

extern "C" void kernel_launch(void* const* d_in, const int* in_sizes, int n_in,
                              void* d_out, int out_size, void* d_ws, size_t ws_size,
                              hipStream_t stream) {
    const int*   z       = (const int*)d_in[0];
    const float* pos     = (const float*)d_in[1];
    const int*   eidx    = (const int*)d_in[2];
    const int*   src     = eidx;
    const int*   dst     = eidx + NE;
    const int*   batch   = (const int*)d_in[3];
    const float* emb     = (const float*)d_in[4];
    const float* mlp_w1  = (const float*)d_in[5];
    const float* mlp_b1  = (const float*)d_in[6];
    const float* mlp_w2  = (const float*)d_in[7];
    const float* mlp_b2  = (const float*)d_in[8];
    const float* conv_w1 = (const float*)d_in[9];
    const float* conv_w2 = (const float*)d_in[10];
    const float* conv_b2 = (const float*)d_in[11];
    const float* lin_w   = (const float*)d_in[12];
    const float* lin_b   = (const float*)d_in[13];
    const float* out1_w  = (const float*)d_in[14];
    const float* out1_b  = (const float*)d_in[15];
    const float* out2_w  = (const float*)d_in[16];
    const float* out2_b  = (const float*)d_in[17];
    float* out = (float*)d_out;

    char* wp = (char*)d_ws;
    auto alloc = [&](size_t bytes) {
        char* p = wp;
        wp += (bytes + 255) & ~(size_t)255;
        return p;
    };
    int*    deg     = (int*)alloc(NN * 4);
    int*    row_ptr = (int*)alloc((NN + 1) * 4);
    int*    cursor  = (int*)alloc(NN * 4);
    int2*   csr_si  = (int2*)alloc((size_t)NE * 8);
    float2* csr_g   = (float2*)alloc((size_t)NE * 8);
    float*  A_tab   = (float*)alloc((size_t)(TBL + 2) * GDIM * 4);
    float*  T1all   = (float*)alloc((size_t)LAYERS * (TBL + 2) * 128 * 4);
    float*  T       = (float*)alloc((size_t)LAYERS * (TBL + 2) * 128 * 4);
    float*  h       = (float*)alloc((size_t)NN * 128 * 4);
    float*  xf      = (float*)alloc((size_t)NN * 128 * 4);
    float*  agg     = (float*)alloc((size_t)NN * 128 * 4);
    float*  t1      = (float*)alloc((size_t)NN * 128 * 4);

    // graph structure
    zero_i32<<<(NN + 255) / 256, 256, 0, stream>>>(deg, NN);
    deg_hist<<<(NE + 255) / 256, 256, 0, stream>>>(dst, deg);
    scan_deg<<<1, 1024, 0, stream>>>(deg, row_ptr, cursor);
    csr_fill<<<(NE + 255) / 256, 256, 0, stream>>>(pos, src, dst, cursor, csr_si, csr_g);

    // filter tables: T[l] = ssp(A_tab @ w1 + b1) @ w2 + b2  (batched over L)
    attr_table<<<(((TBL + 2) * GDIM) + 255) / 256, 256, 0, stream>>>(A_tab);
    const int Mt = TBL + 2;
    const int gt = (Mt + 31) / 32;
    gemm_t<GDIM><<<dim3(gt, LAYERS), 256, 0, stream>>>(
        A_tab, mlp_w1, mlp_b1, nullptr, T1all, Mt, 1,
        0, GDIM * 128, 128, Mt * 128);
    gemm_t<128><<<dim3(gt, LAYERS), 256, 0, stream>>>(
        T1all, mlp_w2, mlp_b2, nullptr, T, Mt, 0,
        Mt * 128, 128 * 128, 128, Mt * 128);

    // node embedding
    h_init<<<(NN * 32 + 255) / 256, 256, 0, stream>>>(z, emb, h);

    const int gn = (NN + 31) / 32;
    for (int l = 0; l < LAYERS; l++) {
        gemm_t<128><<<gn, 256, 0, stream>>>(h, conv_w1 + (size_t)l * 128 * 128,
                                            nullptr, nullptr, xf, NN, 0, 0, 0, 0, 0);
        edge_agg<<<(NN + 3) / 4, 256, 0, stream>>>(row_ptr, csr_si, csr_g,
                                                   T + (size_t)l * Mt * 128, xf, agg);
        gemm_t<128><<<gn, 256, 0, stream>>>(agg, conv_w2 + (size_t)l * 128 * 128,
                                            conv_b2 + l * 128, nullptr, t1, NN, 1, 0, 0, 0, 0);
        gemm_t<128><<<gn, 256, 0, stream>>>(t1, lin_w + (size_t)l * 128 * 128,
                                            lin_b + l * 128, h, h, NN, 0, 0, 0, 0, 0);
    }

    // output head
    gemm_t<128><<<gn, 256, 0, stream>>>(h, out1_w, out1_b, nullptr, xf, NN, 1, 0, 0, 0, 0);
    gemm_t<128><<<gn, 256, 0, stream>>>(xf, out2_w, out2_b, nullptr, agg, NN, 0, 0, 0, 0, 0);

    // per-graph mean
    readout<<<NGRAPH, 128, 0, stream>>>(agg, batch, out);
}

// Round 3
// 1087.423 us; speedup vs baseline: 1.5059x; 1.1764x over previous
//
#include <hip/hip_runtime.h>
#include <math.h>

#define NN 20000
#define NE 640000
#define GDIM 50
#define LAYERS 6
#define NGRAPH 64
#define TBL 2048
#define DMAXF 12.8f

typedef __attribute__((ext_vector_type(8))) short short8;
typedef __attribute__((ext_vector_type(4))) float floatx4;

__device__ __forceinline__ float sspf(float x) {
    float sp = (x > 30.0f) ? x : log1pf(expf(x));
    return sp - 0.69314718055994530942f;
}

__device__ __forceinline__ unsigned short f2bs(float f) {
    union { float f; unsigned int i; } u; u.f = f;
    unsigned int r = u.i + 0x7fffu + ((u.i >> 16) & 1u);
    return (unsigned short)(r >> 16);
}

__device__ __forceinline__ float bs2f(unsigned int bits16) {
    union { unsigned int i; float f; } u; u.i = bits16 << 16;
    return u.f;
}

__global__ void zero_i32(int* p, int n) {
    int i = blockIdx.x * blockDim.x + threadIdx.x;
    if (i < n) p[i] = 0;
}

__global__ void deg_hist(const int* __restrict__ dst, int* __restrict__ deg) {
    int j = blockIdx.x * blockDim.x + threadIdx.x;
    if (j >= NE) return;
    atomicAdd(&deg[dst[j]], 1);
}

// single-block exclusive scan of deg -> row_ptr[0..NN], cursor[0..NN-1]
__global__ void scan_deg(const int* __restrict__ deg, int* __restrict__ row_ptr,
                         int* __restrict__ cursor) {
    __shared__ int part[1024];
    const int n = NN;
    const int PER = 20;
    int t = threadIdx.x;
    int base = t * PER;
    int local[PER];
    int s = 0;
    #pragma unroll
    for (int i = 0; i < PER; i++) {
        int k = base + i;
        local[i] = s;
        if (k < n) s += deg[k];
    }
    part[t] = s;
    __syncthreads();
    for (int off = 1; off < 1024; off <<= 1) {
        int v = (t >= off) ? part[t - off] : 0;
        __syncthreads();
        part[t] += v;
        __syncthreads();
    }
    int offset = (t > 0) ? part[t - 1] : 0;
    #pragma unroll
    for (int i = 0; i < PER; i++) {
        int k = base + i;
        if (k <= n) {
            int v = offset + local[i];
            row_ptr[k] = v;
            if (k < n) cursor[k] = v;
        }
    }
}

// CSR entry: int4{src*64, i0*64, bits(C), bits(C*f)}
__global__ void csr_fill(const float* __restrict__ pos, const int* __restrict__ src,
                         const int* __restrict__ dst, int* __restrict__ cursor,
                         int4* __restrict__ csr) {
    int j = blockIdx.x * blockDim.x + threadIdx.x;
    if (j >= NE) return;
    int s = src[j], tno = dst[j];
    float dx = pos[3*s+0] - pos[3*tno+0];
    float dy = pos[3*s+1] - pos[3*tno+1];
    float dz = pos[3*s+2] - pos[3*tno+2];
    float d = sqrtf(dx*dx + dy*dy + dz*dz);
    float C = 0.5f * (cosf(d * 0.31415926535897931f) + 1.0f);
    float u = d * ((float)TBL / DMAXF);
    u = fminf(u, (float)(TBL + 1));
    int i0 = (int)u; if (i0 > TBL) i0 = TBL;
    float f = u - (float)i0;
    int p = atomicAdd(&cursor[tno], 1);
    int4 e;
    e.x = s * 64;
    e.y = i0 * 64;
    e.z = __float_as_int(C);
    e.w = __float_as_int(C * f);
    csr[p] = e;
}

__global__ void attr_table(float* __restrict__ A) {
    int idx = blockIdx.x * blockDim.x + threadIdx.x;
    const int total = (TBL + 2) * GDIM;
    if (idx >= total) return;
    int i = idx / GDIM, g = idx % GDIM;
    float v = 0.0f;
    if (i <= TBL) {
        float d = (float)i * (DMAXF / (float)TBL);
        float step = 10.0f / 49.0f;
        float off = (float)g * step;
        float coeff = -0.5f / (step * step);
        float dd = d - off;
        v = expf(coeff * dd * dd);
    }
    A[idx] = v;
}

// fp32 tiled GEMM (used only for the K=50 table stage), batched over gridDim.y
template <int K>
__launch_bounds__(256, 2)
__global__ void gemm_t(const float* __restrict__ A, const float* __restrict__ W,
                       const float* __restrict__ bias, float* __restrict__ Y, int M,
                       int act, int aStride, int wStride, int bStride, int yStride) {
    constexpr int KP = (K + 3) & ~3;
    __shared__ __align__(16) float Ws[KP * 128];
    __shared__ __align__(16) float As[32 * KP];
    int l = blockIdx.y;
    A += (size_t)l * aStride;
    W += (size_t)l * wStride;
    if (bias) bias += (size_t)l * bStride;
    Y += (size_t)l * yStride;
    int t = threadIdx.x;
    int row0 = blockIdx.x * 32;
    for (int i = t; i < KP * 128; i += 256) Ws[i] = (i < K * 128) ? W[i] : 0.0f;
    for (int i = t; i < 32 * KP; i += 256) {
        int r = i / KP, k = i % KP;
        float v = 0.f;
        if (k < K && row0 + r < M) v = A[(size_t)(row0 + r) * K + k];
        As[r * KP + k] = v;
    }
    __syncthreads();
    int tx = t & 31, ty = t >> 5;
    int c0 = tx * 4, r0 = ty * 4;
    float acc[4][4] = {{0.f}};
    #pragma unroll 4
    for (int k = 0; k < KP; k += 4) {
        float4 a0 = *(const float4*)&As[(r0 + 0) * KP + k];
        float4 a1 = *(const float4*)&As[(r0 + 1) * KP + k];
        float4 a2 = *(const float4*)&As[(r0 + 2) * KP + k];
        float4 a3 = *(const float4*)&As[(r0 + 3) * KP + k];
        float4 w0 = *(const float4*)&Ws[(k + 0) * 128 + c0];
        float4 w1 = *(const float4*)&Ws[(k + 1) * 128 + c0];
        float4 w2 = *(const float4*)&Ws[(k + 2) * 128 + c0];
        float4 w3 = *(const float4*)&Ws[(k + 3) * 128 + c0];
        float av[4][4] = {{a0.x,a0.y,a0.z,a0.w},{a1.x,a1.y,a1.z,a1.w},
                          {a2.x,a2.y,a2.z,a2.w},{a3.x,a3.y,a3.z,a3.w}};
        float wv[4][4] = {{w0.x,w0.y,w0.z,w0.w},{w1.x,w1.y,w1.z,w1.w},
                          {w2.x,w2.y,w2.z,w2.w},{w3.x,w3.y,w3.z,w3.w}};
        #pragma unroll
        for (int i = 0; i < 4; i++)
            #pragma unroll
            for (int j = 0; j < 4; j++)
                #pragma unroll
                for (int q = 0; q < 4; q++)
                    acc[i][j] += av[i][q] * wv[q][j];
    }
    float b0 = 0.f, b1 = 0.f, b2 = 0.f, b3 = 0.f;
    if (bias) { b0 = bias[c0]; b1 = bias[c0+1]; b2 = bias[c0+2]; b3 = bias[c0+3]; }
    #pragma unroll
    for (int i = 0; i < 4; i++) {
        int r = row0 + r0 + i;
        if (r >= M) break;
        float4 v;
        v.x = acc[i][0] + b0; v.y = acc[i][1] + b1; v.z = acc[i][2] + b2; v.w = acc[i][3] + b3;
        if (act == 1) { v.x = sspf(v.x); v.y = sspf(v.y); v.z = sspf(v.z); v.w = sspf(v.w); }
        *(float4*)&Y[(size_t)r * 128 + c0] = v;
    }
}

// transpose + quantize weight matrices: Wt[n][k] = bf16(W[k][n]); gridDim.z = matrix
__global__ void wprep(const float* __restrict__ W, unsigned short* __restrict__ Wt) {
    __shared__ float tile[32][33];
    int mz = blockIdx.z;
    const float* Wm = W + (size_t)mz * 16384;
    unsigned short* Wo = Wt + (size_t)mz * 16384;
    int bx = blockIdx.x * 32, by = blockIdx.y * 32;
    int tx = threadIdx.x & 31, ty = threadIdx.x >> 5;
    for (int r = ty; r < 32; r += 8) tile[r][tx] = Wm[(by + r) * 128 + bx + tx];
    __syncthreads();
    for (int r = ty; r < 32; r += 8) Wo[(bx + r) * 128 + by + tx] = f2bs(tile[tx][r]);
}

// bf16 MFMA GEMM: Y[M,128] = act(A[M,128] @ Wt^T + bias) + resid
// Wt is [n][k] bf16. One wave per 16 rows. Batched over gridDim.y.
__launch_bounds__(256)
__global__ void gemm_mfma(const float* __restrict__ A, const unsigned short* __restrict__ Wt,
                          const float* __restrict__ bias, const float* __restrict__ resid,
                          float* __restrict__ Yf, unsigned short* __restrict__ Yb,
                          int M, int act,
                          int aStride, int wStride, int bStride, int yStride) {
    int l = blockIdx.y;
    A += (size_t)l * aStride;
    Wt += (size_t)l * wStride;
    if (bias) bias += (size_t)l * bStride;
    if (Yf) Yf += (size_t)l * yStride;
    int wid = blockIdx.x * 4 + (threadIdx.x >> 6);
    int lane = threadIdx.x & 63;
    int row0 = wid * 16;
    if (row0 >= M) return;
    int lm = lane & 15;
    int lk = (lane >> 4) * 8;
    int arow = row0 + lm;
    int arowc = (arow < M) ? arow : (M - 1);
    const float* Ap = A + (size_t)arowc * 128;
    floatx4 acc[8];
    #pragma unroll
    for (int i = 0; i < 8; i++) acc[i] = (floatx4){0.f, 0.f, 0.f, 0.f};
    #pragma unroll
    for (int kq = 0; kq < 4; kq++) {
        int k0 = kq * 32;
        float4 a0 = *(const float4*)(Ap + k0 + lk);
        float4 a1 = *(const float4*)(Ap + k0 + lk + 4);
        short8 af;
        af[0] = (short)f2bs(a0.x); af[1] = (short)f2bs(a0.y);
        af[2] = (short)f2bs(a0.z); af[3] = (short)f2bs(a0.w);
        af[4] = (short)f2bs(a1.x); af[5] = (short)f2bs(a1.y);
        af[6] = (short)f2bs(a1.z); af[7] = (short)f2bs(a1.w);
        #pragma unroll
        for (int ct = 0; ct < 8; ct++) {
            const unsigned short* wp = Wt + ((size_t)(ct * 16 + lm)) * 128 + k0 + lk;
            short8 bf = *(const short8*)wp;
            acc[ct] = __builtin_amdgcn_mfma_f32_16x16x32_bf16(af, bf, acc[ct], 0, 0, 0);
        }
    }
    // epilogue: C/D layout col=lane&15, row=(lane>>4)*4+reg
    int orow = (lane >> 4) * 4;
    #pragma unroll
    for (int ct = 0; ct < 8; ct++) {
        int c = ct * 16 + lm;
        float b = bias ? bias[c] : 0.f;
        #pragma unroll
        for (int r = 0; r < 4; r++) {
            int rr = row0 + orow + r;
            if (rr >= M) continue;
            float v = acc[ct][r] + b;
            if (act) v = sspf(v);
            if (resid) v += resid[(size_t)rr * 128 + c];
            if (Yf) Yf[(size_t)rr * 128 + c] = v;
            if (Yb) Yb[(size_t)rr * 128 + c] = f2bs(v);
        }
    }
}

// quantize filter table to interleaved (W, dW) bf16 pairs:
// Tb[(l*2049+i)*64+lane] = uint2{ dW0<<16|W0 , dW1<<16|W1 } for channels 2*lane,2*lane+1
__global__ void tquant(const float* __restrict__ T, uint2* __restrict__ Tb) {
    int idx = blockIdx.x * blockDim.x + threadIdx.x;
    const int total = LAYERS * (TBL + 1) * 64;
    if (idx >= total) return;
    int lane = idx & 63;
    int li = idx >> 6;
    int i = li % (TBL + 1);
    int l = li / (TBL + 1);
    const float* row = T + ((size_t)l * (TBL + 2) + i) * 128 + lane * 2;
    float w0 = row[0], w1 = row[1];
    float d0 = row[128] - w0, d1 = row[129] - w1;
    uint2 o;
    o.x = ((unsigned)f2bs(d0) << 16) | f2bs(w0);
    o.y = ((unsigned)f2bs(d1) << 16) | f2bs(w1);
    Tb[idx] = o;
}

__global__ void h_init(const int* __restrict__ z, const float* __restrict__ emb,
                       float* __restrict__ h) {
    int idx = blockIdx.x * blockDim.x + threadIdx.x;
    if (idx >= NN * 32) return;
    int n = idx >> 5, q = idx & 31;
    ((float4*)h)[n * 32 + q] = ((const float4*)emb)[z[n] * 32 + q];
}

// one wave per node: agg = sum_e xfb[src] * (C*W + C*f*dW)
__launch_bounds__(256)
__global__ void edge_agg(const int* __restrict__ row_ptr, const int4* __restrict__ csr,
                         const uint2* __restrict__ Tb, const unsigned int* __restrict__ xfb,
                         float* __restrict__ agg) {
    int wave = threadIdx.x >> 6;
    int lane = threadIdx.x & 63;
    int n = blockIdx.x * 4 + wave;
    if (n >= NN) return;
    int e0 = row_ptr[n], e1 = row_ptr[n + 1];
    float ax = 0.f, ay = 0.f;
    int e = e0;
    for (; e + 8 <= e1; e += 8) {
        int4 ed[8]; uint2 tw[8]; unsigned int xv[8];
        #pragma unroll
        for (int q = 0; q < 8; q++) ed[q] = csr[e + q];
        #pragma unroll
        for (int q = 0; q < 8; q++) {
            tw[q] = Tb[ed[q].y + lane];
            xv[q] = xfb[ed[q].x + lane];
        }
        #pragma unroll
        for (int q = 0; q < 8; q++) {
            float gC = __int_as_float(ed[q].z);
            float gF = __int_as_float(ed[q].w);
            float w0 = bs2f(tw[q].x & 0xffffu), d0 = bs2f(tw[q].x >> 16);
            float w1 = bs2f(tw[q].y & 0xffffu), d1 = bs2f(tw[q].y >> 16);
            float xx = bs2f(xv[q] & 0xffffu), xy = bs2f(xv[q] >> 16);
            ax += xx * (gC * w0 + gF * d0);
            ay += xy * (gC * w1 + gF * d1);
        }
    }
    for (; e < e1; e++) {
        int4 ed = csr[e];
        uint2 tw = Tb[ed.y + lane];
        unsigned int xv = xfb[ed.x + lane];
        float gC = __int_as_float(ed.z);
        float gF = __int_as_float(ed.w);
        float w0 = bs2f(tw.x & 0xffffu), d0 = bs2f(tw.x >> 16);
        float w1 = bs2f(tw.y & 0xffffu), d1 = bs2f(tw.y >> 16);
        float xx = bs2f(xv & 0xffffu), xy = bs2f(xv >> 16);
        ax += xx * (gC * w0 + gF * d0);
        ay += xy * (gC * w1 + gF * d1);
    }
    float2 r; r.x = ax; r.y = ay;
    ((float2*)agg)[(size_t)n * 64 + lane] = r;
}

__global__ void readout(const float* __restrict__ hout, const int* __restrict__ batch,
                        float* __restrict__ out) {
    int g = blockIdx.x;
    int c = threadIdx.x;
    __shared__ int sh[2];
    if (c < 2) {
        int target = g + c;
        int lo = 0, hi = NN;
        while (lo < hi) {
            int mid = (lo + hi) >> 1;
            if (batch[mid] < target) lo = mid + 1; else hi = mid;
        }
        sh[c] = lo;
    }
    __syncthreads();
    int lo = sh[0], hi = sh[1];
    float s = 0.f;
    for (int n = lo; n < hi; n++) s += hout[(size_t)n * 128 + c];
    int cnt = hi - lo;
    out[g * 128 + c] = s / (float)(cnt > 0 ? cnt : 1);
}

extern "C" void kernel_launch(void* const* d_in, const int* in_sizes, int n_in,
                              void* d_out, int out_size, void* d_ws, size_t ws_size,
                              hipStream_t stream) {
    const int*   z       = (const int*)d_in[0];
    const float* pos     = (const float*)d_in[1];
    const int*   eidx    = (const int*)d_in[2];
    const int*   src     = eidx;
    const int*   dst     = eidx + NE;
    const int*   batch   = (const int*)d_in[3];
    const float* emb     = (const float*)d_in[4];
    const float* mlp_w1  = (const float*)d_in[5];
    const float* mlp_b1  = (const float*)d_in[6];
    const float* mlp_w2  = (const float*)d_in[7];
    const float* mlp_b2  = (const float*)d_in[8];
    const float* conv_w1 = (const float*)d_in[9];
    const float* conv_w2 = (const float*)d_in[10];
    const float* conv_b2 = (const float*)d_in[11];
    const float* lin_w   = (const float*)d_in[12];
    const float* lin_b   = (const float*)d_in[13];
    const float* out1_w  = (const float*)d_in[14];
    const float* out1_b  = (const float*)d_in[15];
    const float* out2_w  = (const float*)d_in[16];
    const float* out2_b  = (const float*)d_in[17];
    float* out = (float*)d_out;

    char* wp = (char*)d_ws;
    auto alloc = [&](size_t bytes) {
        char* p = wp;
        wp += (bytes + 255) & ~(size_t)255;
        return p;
    };
    const int Mt = TBL + 2;
    int*    deg     = (int*)alloc(NN * 4);
    int*    row_ptr = (int*)alloc((NN + 1) * 4);
    int*    cursor  = (int*)alloc(NN * 4);
    int4*   csr     = (int4*)alloc((size_t)NE * 16);
    float*  A_tab   = (float*)alloc((size_t)Mt * GDIM * 4);
    float*  T1all   = (float*)alloc(((size_t)LAYERS * Mt * 128 + 4096) * 4);
    float*  T       = (float*)alloc((size_t)LAYERS * Mt * 128 * 4);
    uint2*  Tb      = (uint2*)alloc((size_t)LAYERS * (TBL + 1) * 64 * 8);
    float*  h       = (float*)alloc((size_t)NN * 128 * 4);
    float*  t1      = (float*)alloc((size_t)NN * 128 * 4);
    float*  agg     = (float*)alloc((size_t)NN * 128 * 4);
    unsigned short* xfb = (unsigned short*)alloc((size_t)NN * 128 * 2);
    unsigned short* mlp_w2t  = (unsigned short*)alloc((size_t)LAYERS * 16384 * 2);
    unsigned short* conv_w1t = (unsigned short*)alloc((size_t)LAYERS * 16384 * 2);
    unsigned short* conv_w2t = (unsigned short*)alloc((size_t)LAYERS * 16384 * 2);
    unsigned short* lin_wt   = (unsigned short*)alloc((size_t)LAYERS * 16384 * 2);
    unsigned short* out1_wt  = (unsigned short*)alloc((size_t)16384 * 2);
    unsigned short* out2_wt  = (unsigned short*)alloc((size_t)16384 * 2);

    // graph structure
    zero_i32<<<(NN + 255) / 256, 256, 0, stream>>>(deg, NN);
    deg_hist<<<(NE + 255) / 256, 256, 0, stream>>>(dst, deg);
    scan_deg<<<1, 1024, 0, stream>>>(deg, row_ptr, cursor);
    csr_fill<<<(NE + 255) / 256, 256, 0, stream>>>(pos, src, dst, cursor, csr);

    // weight prep (transpose + bf16)
    dim3 wg(4, 4, LAYERS);
    wprep<<<wg, 256, 0, stream>>>(mlp_w2, mlp_w2t);
    wprep<<<wg, 256, 0, stream>>>(conv_w1, conv_w1t);
    wprep<<<wg, 256, 0, stream>>>(conv_w2, conv_w2t);
    wprep<<<wg, 256, 0, stream>>>(lin_w, lin_wt);
    wprep<<<dim3(4, 4, 1), 256, 0, stream>>>(out1_w, out1_wt);
    wprep<<<dim3(4, 4, 1), 256, 0, stream>>>(out2_w, out2_wt);

    // filter tables
    attr_table<<<((Mt * GDIM) + 255) / 256, 256, 0, stream>>>(A_tab);
    const int gt32 = (Mt + 31) / 32;
    gemm_t<GDIM><<<dim3(gt32, LAYERS), 256, 0, stream>>>(
        A_tab, mlp_w1, mlp_b1, T1all, Mt, 1, 0, GDIM * 128, 128, Mt * 128);
    const int gtw = ((Mt + 15) / 16 + 3) / 4;
    gemm_mfma<<<dim3(gtw, LAYERS), 256, 0, stream>>>(
        T1all, mlp_w2t, mlp_b2, nullptr, T, nullptr, Mt, 0,
        Mt * 128, 16384, 128, Mt * 128);
    tquant<<<(LAYERS * (TBL + 1) * 64 + 255) / 256, 256, 0, stream>>>(T, Tb);

    // node embedding
    h_init<<<(NN * 32 + 255) / 256, 256, 0, stream>>>(z, emb, h);

    const int gn = ((NN + 15) / 16 + 3) / 4;   // 313 blocks
    for (int l = 0; l < LAYERS; l++) {
        // xf(bf16) = h @ conv_w1[l]
        gemm_mfma<<<gn, 256, 0, stream>>>(h, conv_w1t + (size_t)l * 16384,
                                          nullptr, nullptr, nullptr, xfb, NN, 0, 0, 0, 0, 0);
        edge_agg<<<(NN + 3) / 4, 256, 0, stream>>>(row_ptr, csr,
                                                   Tb + (size_t)l * (TBL + 1) * 64,
                                                   (const unsigned int*)xfb, agg);
        // t1 = ssp(agg @ conv_w2[l] + b2)
        gemm_mfma<<<gn, 256, 0, stream>>>(agg, conv_w2t + (size_t)l * 16384,
                                          conv_b2 + l * 128, nullptr, t1, nullptr, NN, 1, 0, 0, 0, 0);
        // h = h + t1 @ lin_w[l] + lin_b[l]
        gemm_mfma<<<gn, 256, 0, stream>>>(t1, lin_wt + (size_t)l * 16384,
                                          lin_b + l * 128, h, h, nullptr, NN, 0, 0, 0, 0, 0);
    }

    // output head
    gemm_mfma<<<gn, 256, 0, stream>>>(h, out1_wt, out1_b, nullptr, t1, nullptr, NN, 1, 0, 0, 0, 0);
    gemm_mfma<<<gn, 256, 0, stream>>>(t1, out2_wt, out2_b, nullptr, agg, nullptr, NN, 0, 0, 0, 0, 0);

    readout<<<NGRAPH, 128, 0, stream>>>(agg, batch, out);
}

// Round 4
// 1034.530 us; speedup vs baseline: 1.5829x; 1.0511x over previous
//
#include <hip/hip_runtime.h>
#include <math.h>

#define NN 20000
#define NE 640000
#define GDIM 50
#define LAYERS 6
#define NGRAPH 64
#define TBL 2048
#define DMAXF 12.8f
#define G2_PAD 136   // 128 cols + 8 pad (shorts) -> 272B row stride in LDS

typedef __attribute__((ext_vector_type(8))) short short8;
typedef __attribute__((ext_vector_type(4))) float floatx4;

__device__ __forceinline__ float sspf(float x) {
    float sp = (x > 30.0f) ? x : log1pf(expf(x));
    return sp - 0.69314718055994530942f;
}

__device__ __forceinline__ unsigned short f2bs(float f) {
    union { float f; unsigned int i; } u; u.f = f;
    unsigned int r = u.i + 0x7fffu + ((u.i >> 16) & 1u);
    return (unsigned short)(r >> 16);
}

__device__ __forceinline__ float bs2f(unsigned int bits16) {
    union { unsigned int i; float f; } u; u.i = bits16 << 16;
    return u.f;
}

__device__ __forceinline__ short8 pack_bf16x8(float4 a, float4 b) {
    short8 o;
    o[0] = (short)f2bs(a.x); o[1] = (short)f2bs(a.y);
    o[2] = (short)f2bs(a.z); o[3] = (short)f2bs(a.w);
    o[4] = (short)f2bs(b.x); o[5] = (short)f2bs(b.y);
    o[6] = (short)f2bs(b.z); o[7] = (short)f2bs(b.w);
    return o;
}

// zero deg + zero out + fill gaussian attr table, one launch
__global__ void init_misc(int* __restrict__ deg, float* __restrict__ out,
                          float* __restrict__ A) {
    int idx = blockIdx.x * blockDim.x + threadIdx.x;
    if (idx < NN) { deg[idx] = 0; return; }
    int j = idx - NN;
    if (j < NGRAPH * 128) { out[j] = 0.f; return; }
    j -= NGRAPH * 128;
    const int total = (TBL + 2) * GDIM;
    if (j >= total) return;
    int i = j / GDIM, g = j % GDIM;
    float v = 0.0f;
    if (i <= TBL) {
        float d = (float)i * (DMAXF / (float)TBL);
        float step = 10.0f / 49.0f;
        float off = (float)g * step;
        float coeff = -0.5f / (step * step);
        float dd = d - off;
        v = expf(coeff * dd * dd);
    }
    A[j] = v;
}

__global__ void deg_hist(const int* __restrict__ dst, int* __restrict__ deg) {
    int j = blockIdx.x * blockDim.x + threadIdx.x;
    if (j >= NE) return;
    atomicAdd(&deg[dst[j]], 1);
}

__global__ void scan_deg(const int* __restrict__ deg, int* __restrict__ row_ptr,
                         int* __restrict__ cursor) {
    __shared__ int part[1024];
    const int n = NN;
    const int PER = 20;
    int t = threadIdx.x;
    int base = t * PER;
    int local[PER];
    int s = 0;
    #pragma unroll
    for (int i = 0; i < PER; i++) {
        int k = base + i;
        local[i] = s;
        if (k < n) s += deg[k];
    }
    part[t] = s;
    __syncthreads();
    for (int off = 1; off < 1024; off <<= 1) {
        int v = (t >= off) ? part[t - off] : 0;
        __syncthreads();
        part[t] += v;
        __syncthreads();
    }
    int offset = (t > 0) ? part[t - 1] : 0;
    #pragma unroll
    for (int i = 0; i < PER; i++) {
        int k = base + i;
        if (k <= n) {
            int v = offset + local[i];
            row_ptr[k] = v;
            if (k < n) cursor[k] = v;
        }
    }
}

// CSR entry: int2{ (i0<<15)|src , bits(f) }   (cutoff C folded into table)
__global__ void csr_fill(const float* __restrict__ pos, const int* __restrict__ src,
                         const int* __restrict__ dst, int* __restrict__ cursor,
                         int2* __restrict__ csr) {
    int j = blockIdx.x * blockDim.x + threadIdx.x;
    if (j >= NE) return;
    int s = src[j], tno = dst[j];
    float dx = pos[3*s+0] - pos[3*tno+0];
    float dy = pos[3*s+1] - pos[3*tno+1];
    float dz = pos[3*s+2] - pos[3*tno+2];
    float d = sqrtf(dx*dx + dy*dy + dz*dz);
    float u = d * ((float)TBL / DMAXF);
    u = fminf(u, (float)(TBL + 1));
    int i0 = (int)u; if (i0 > TBL) i0 = TBL;
    float f = u - (float)i0;
    int p = atomicAdd(&cursor[tno], 1);
    csr[p] = make_int2((i0 << 15) | s, __float_as_int(f));
}

// fp32 tiled GEMM for the K=50 table stage only, batched over gridDim.y
template <int K>
__launch_bounds__(256, 2)
__global__ void gemm_t(const float* __restrict__ A, const float* __restrict__ W,
                       const float* __restrict__ bias, float* __restrict__ Y, int M,
                       int act, int aStride, int wStride, int bStride, int yStride) {
    constexpr int KP = (K + 3) & ~3;
    __shared__ __align__(16) float Ws[KP * 128];
    __shared__ __align__(16) float As[32 * KP];
    int l = blockIdx.y;
    A += (size_t)l * aStride;
    W += (size_t)l * wStride;
    if (bias) bias += (size_t)l * bStride;
    Y += (size_t)l * yStride;
    int t = threadIdx.x;
    int row0 = blockIdx.x * 32;
    for (int i = t; i < KP * 128; i += 256) Ws[i] = (i < K * 128) ? W[i] : 0.0f;
    for (int i = t; i < 32 * KP; i += 256) {
        int r = i / KP, k = i % KP;
        float v = 0.f;
        if (k < K && row0 + r < M) v = A[(size_t)(row0 + r) * K + k];
        As[r * KP + k] = v;
    }
    __syncthreads();
    int tx = t & 31, ty = t >> 5;
    int c0 = tx * 4, r0 = ty * 4;
    float acc[4][4] = {{0.f}};
    #pragma unroll 4
    for (int k = 0; k < KP; k += 4) {
        float4 a0 = *(const float4*)&As[(r0 + 0) * KP + k];
        float4 a1 = *(const float4*)&As[(r0 + 1) * KP + k];
        float4 a2 = *(const float4*)&As[(r0 + 2) * KP + k];
        float4 a3 = *(const float4*)&As[(r0 + 3) * KP + k];
        float4 w0 = *(const float4*)&Ws[(k + 0) * 128 + c0];
        float4 w1 = *(const float4*)&Ws[(k + 1) * 128 + c0];
        float4 w2 = *(const float4*)&Ws[(k + 2) * 128 + c0];
        float4 w3 = *(const float4*)&Ws[(k + 3) * 128 + c0];
        float av[4][4] = {{a0.x,a0.y,a0.z,a0.w},{a1.x,a1.y,a1.z,a1.w},
                          {a2.x,a2.y,a2.z,a2.w},{a3.x,a3.y,a3.z,a3.w}};
        float wv[4][4] = {{w0.x,w0.y,w0.z,w0.w},{w1.x,w1.y,w1.z,w1.w},
                          {w2.x,w2.y,w2.z,w2.w},{w3.x,w3.y,w3.z,w3.w}};
        #pragma unroll
        for (int i = 0; i < 4; i++)
            #pragma unroll
            for (int j = 0; j < 4; j++)
                #pragma unroll
                for (int q = 0; q < 4; q++)
                    acc[i][j] += av[i][q] * wv[q][j];
    }
    float b0 = 0.f, b1 = 0.f, b2 = 0.f, b3 = 0.f;
    if (bias) { b0 = bias[c0]; b1 = bias[c0+1]; b2 = bias[c0+2]; b3 = bias[c0+3]; }
    #pragma unroll
    for (int i = 0; i < 4; i++) {
        int r = row0 + r0 + i;
        if (r >= M) break;
        float4 v;
        v.x = acc[i][0] + b0; v.y = acc[i][1] + b1; v.z = acc[i][2] + b2; v.w = acc[i][3] + b3;
        if (act == 1) { v.x = sspf(v.x); v.y = sspf(v.y); v.z = sspf(v.z); v.w = sspf(v.w); }
        *(float4*)&Y[(size_t)r * 128 + c0] = v;
    }
}

// batched transpose + bf16 quantize of all 26 weight matrices in one launch
struct WArgs { const float* s[26]; unsigned short* d[26]; };
__global__ void wprep_all(WArgs a) {
    __shared__ float tile[32][33];
    int mz = blockIdx.z;
    const float* Wm = a.s[mz];
    unsigned short* Wo = a.d[mz];
    int bx = blockIdx.x * 32, by = blockIdx.y * 32;
    int tx = threadIdx.x & 31, ty = threadIdx.x >> 5;
    for (int r = ty; r < 32; r += 8) tile[r][tx] = Wm[(by + r) * 128 + bx + tx];
    __syncthreads();
    for (int r = ty; r < 32; r += 8) Wo[(bx + r) * 128 + by + tx] = f2bs(tile[tx][r]);
}

// bf16 MFMA GEMM, 32 rows/wave: Y = act(A[M,128] @ Wt^T + bias) + resid
__launch_bounds__(256)
__global__ void gemm_mfma32(const float* __restrict__ A, const unsigned short* __restrict__ Wt,
                            const float* __restrict__ bias, const float* __restrict__ resid,
                            float* __restrict__ Yf, unsigned short* __restrict__ Yb,
                            int M, int act,
                            int aStride, int wStride, int bStride, int yStride) {
    int l = blockIdx.y;
    A += (size_t)l * aStride;
    Wt += (size_t)l * wStride;
    if (bias) bias += (size_t)l * bStride;
    if (Yf) Yf += (size_t)l * yStride;
    int wid = blockIdx.x * 4 + (threadIdx.x >> 6);
    int lane = threadIdx.x & 63;
    int row0 = wid * 32;
    if (row0 >= M) return;
    int lm = lane & 15, lk = (lane >> 4) * 8;
    int r0a = row0 + lm;       r0a = (r0a < M) ? r0a : M - 1;
    int r1a = row0 + 16 + lm;  r1a = (r1a < M) ? r1a : M - 1;
    const float* Ap0 = A + (size_t)r0a * 128;
    const float* Ap1 = A + (size_t)r1a * 128;
    floatx4 acc0[8], acc1[8];
    #pragma unroll
    for (int i = 0; i < 8; i++) { acc0[i] = (floatx4){0,0,0,0}; acc1[i] = (floatx4){0,0,0,0}; }
    #pragma unroll
    for (int kq = 0; kq < 4; kq++) {
        int k0 = kq * 32;
        float4 p0 = *(const float4*)(Ap0 + k0 + lk);
        float4 p1 = *(const float4*)(Ap0 + k0 + lk + 4);
        float4 q0 = *(const float4*)(Ap1 + k0 + lk);
        float4 q1 = *(const float4*)(Ap1 + k0 + lk + 4);
        short8 af0 = pack_bf16x8(p0, p1);
        short8 af1 = pack_bf16x8(q0, q1);
        #pragma unroll
        for (int ct = 0; ct < 8; ct++) {
            short8 bf = *(const short8*)(Wt + (size_t)(ct * 16 + lm) * 128 + k0 + lk);
            acc0[ct] = __builtin_amdgcn_mfma_f32_16x16x32_bf16(af0, bf, acc0[ct], 0, 0, 0);
            acc1[ct] = __builtin_amdgcn_mfma_f32_16x16x32_bf16(af1, bf, acc1[ct], 0, 0, 0);
        }
    }
    int orow = (lane >> 4) * 4;
    #pragma unroll
    for (int tt = 0; tt < 2; tt++) {
        floatx4* ac = tt ? acc1 : acc0;
        int rbase = row0 + tt * 16 + orow;
        #pragma unroll
        for (int ct = 0; ct < 8; ct++) {
            int c = ct * 16 + lm;
            float b = bias ? bias[c] : 0.f;
            #pragma unroll
            for (int r = 0; r < 4; r++) {
                int rr = rbase + r;
                if (rr >= M) continue;
                float v = ac[ct][r] + b;
                if (act) v = sspf(v);
                if (resid) v += resid[(size_t)rr * 128 + c];
                if (Yf) Yf[(size_t)rr * 128 + c] = v;
                if (Yb) Yb[(size_t)rr * 128 + c] = f2bs(v);
            }
        }
    }
}

// fused double GEMM: Yf = ssp(A @ W1t^T + b1) @ W2t^T + b2 [+ resid]
// 32 rows/wave, per-wave private LDS round-trip (C-layout -> A-layout), no barrier
__launch_bounds__(256)
__global__ void gemm2(const float* __restrict__ A, const unsigned short* __restrict__ W1t,
                      const float* __restrict__ b1, const unsigned short* __restrict__ W2t,
                      const float* __restrict__ b2, const float* __restrict__ resid,
                      float* __restrict__ Yf, int M) {
    __shared__ unsigned short t1s[4 * 32 * G2_PAD];
    int wv = threadIdx.x >> 6;
    int lane = threadIdx.x & 63;
    unsigned short* Ls = t1s + wv * 32 * G2_PAD;
    int wid = blockIdx.x * 4 + wv;
    int row0 = wid * 32;
    if (row0 >= M) return;
    int lm = lane & 15, lk = (lane >> 4) * 8;
    int orow = (lane >> 4) * 4;
    // ---- phase 1: t1 = ssp(A @ W1t^T + b1) -> LDS (bf16) ----
    {
        int r0a = row0 + lm;       r0a = (r0a < M) ? r0a : M - 1;
        int r1a = row0 + 16 + lm;  r1a = (r1a < M) ? r1a : M - 1;
        const float* Ap0 = A + (size_t)r0a * 128;
        const float* Ap1 = A + (size_t)r1a * 128;
        floatx4 acc0[8], acc1[8];
        #pragma unroll
        for (int i = 0; i < 8; i++) { acc0[i] = (floatx4){0,0,0,0}; acc1[i] = (floatx4){0,0,0,0}; }
        #pragma unroll
        for (int kq = 0; kq < 4; kq++) {
            int k0 = kq * 32;
            float4 p0 = *(const float4*)(Ap0 + k0 + lk);
            float4 p1 = *(const float4*)(Ap0 + k0 + lk + 4);
            float4 q0 = *(const float4*)(Ap1 + k0 + lk);
            float4 q1 = *(const float4*)(Ap1 + k0 + lk + 4);
            short8 af0 = pack_bf16x8(p0, p1);
            short8 af1 = pack_bf16x8(q0, q1);
            #pragma unroll
            for (int ct = 0; ct < 8; ct++) {
                short8 bf = *(const short8*)(W1t + (size_t)(ct * 16 + lm) * 128 + k0 + lk);
                acc0[ct] = __builtin_amdgcn_mfma_f32_16x16x32_bf16(af0, bf, acc0[ct], 0, 0, 0);
                acc1[ct] = __builtin_amdgcn_mfma_f32_16x16x32_bf16(af1, bf, acc1[ct], 0, 0, 0);
            }
        }
        #pragma unroll
        for (int tt = 0; tt < 2; tt++) {
            floatx4* ac = tt ? acc1 : acc0;
            #pragma unroll
            for (int ct = 0; ct < 8; ct++) {
                float b = b1[ct * 16 + lm];
                #pragma unroll
                for (int r = 0; r < 4; r++) {
                    float v = sspf(ac[ct][r] + b);
                    Ls[(tt * 16 + orow + r) * G2_PAD + ct * 16 + lm] = f2bs(v);
                }
            }
        }
    }
    // ---- phase 2: Yf = t1 @ W2t^T + b2 (+resid) ----  (same-wave LDS dep; compiler waits lgkm)
    floatx4 c0[8], c1[8];
    #pragma unroll
    for (int i = 0; i < 8; i++) { c0[i] = (floatx4){0,0,0,0}; c1[i] = (floatx4){0,0,0,0}; }
    #pragma unroll
    for (int kq = 0; kq < 4; kq++) {
        int k0 = kq * 32;
        short8 a0 = *(const short8*)&Ls[lm * G2_PAD + k0 + lk];
        short8 a1 = *(const short8*)&Ls[(16 + lm) * G2_PAD + k0 + lk];
        #pragma unroll
        for (int ct = 0; ct < 8; ct++) {
            short8 bf = *(const short8*)(W2t + (size_t)(ct * 16 + lm) * 128 + k0 + lk);
            c0[ct] = __builtin_amdgcn_mfma_f32_16x16x32_bf16(a0, bf, c0[ct], 0, 0, 0);
            c1[ct] = __builtin_amdgcn_mfma_f32_16x16x32_bf16(a1, bf, c1[ct], 0, 0, 0);
        }
    }
    #pragma unroll
    for (int tt = 0; tt < 2; tt++) {
        floatx4* ac = tt ? c1 : c0;
        int rbase = row0 + tt * 16 + orow;
        #pragma unroll
        for (int ct = 0; ct < 8; ct++) {
            int c = ct * 16 + lm;
            float b = b2[c];
            #pragma unroll
            for (int r = 0; r < 4; r++) {
                int rr = rbase + r;
                if (rr >= M) continue;
                float v = ac[ct][r] + b;
                if (resid) v += resid[(size_t)rr * 128 + c];
                Yf[(size_t)rr * 128 + c] = v;
            }
        }
    }
}

// fold cutoff C(d) into table; store interleaved (T', dT') bf16 pairs per channel pair
__global__ void tquant(const float* __restrict__ T, uint2* __restrict__ Tb) {
    int idx = blockIdx.x * blockDim.x + threadIdx.x;
    const int total = LAYERS * (TBL + 1) * 64;
    if (idx >= total) return;
    int lane = idx & 63;
    int li = idx >> 6;
    int i = li % (TBL + 1);
    int l = li / (TBL + 1);
    float d0 = (float)i * (DMAXF / (float)TBL);
    float d1 = (float)(i + 1) * (DMAXF / (float)TBL);
    float C0 = 0.5f * (cosf(d0 * 0.31415926535897931f) + 1.0f);
    float C1 = 0.5f * (cosf(d1 * 0.31415926535897931f) + 1.0f);
    const float* row = T + ((size_t)l * (TBL + 2) + i) * 128 + lane * 2;
    float w0 = row[0] * C0,   w1 = row[1] * C0;
    float n0 = row[128] * C1, n1 = row[129] * C1;
    uint2 o;
    o.x = ((unsigned)f2bs(n0 - w0) << 16) | f2bs(w0);
    o.y = ((unsigned)f2bs(n1 - w1) << 16) | f2bs(w1);
    Tb[idx] = o;
}

__global__ void h_init(const int* __restrict__ z, const float* __restrict__ emb,
                       float* __restrict__ h) {
    int idx = blockIdx.x * blockDim.x + threadIdx.x;
    if (idx >= NN * 32) return;
    int n = idx >> 5, q = idx & 31;
    ((float4*)h)[n * 32 + q] = ((const float4*)emb)[z[n] * 32 + q];
}

// one wave per node: agg = sum_e xfb[src] * (T'[i0] + f*dT')
__launch_bounds__(256)
__global__ void edge_agg(const int* __restrict__ row_ptr, const int2* __restrict__ csr,
                         const uint2* __restrict__ Tb, const unsigned int* __restrict__ xfb,
                         float* __restrict__ agg) {
    int wave = threadIdx.x >> 6;
    int lane = threadIdx.x & 63;
    int n = blockIdx.x * 4 + wave;
    if (n >= NN) return;
    int e0 = row_ptr[n], e1 = row_ptr[n + 1];
    float ax = 0.f, ay = 0.f;
    int e = e0;
    for (; e + 8 <= e1; e += 8) {
        int2 ed[8]; uint2 tw[8]; unsigned int xv[8];
        #pragma unroll
        for (int q = 0; q < 8; q++) ed[q] = csr[e + q];
        #pragma unroll
        for (int q = 0; q < 8; q++) {
            unsigned int px = (unsigned int)ed[q].x;
            tw[q] = Tb[(px >> 15) * 64 + lane];
            xv[q] = xfb[(px & 0x7fffu) * 64 + lane];
        }
        #pragma unroll
        for (int q = 0; q < 8; q++) {
            float f = __int_as_float(ed[q].y);
            float w0 = bs2f(tw[q].x & 0xffffu), dd0 = bs2f(tw[q].x >> 16);
            float w1 = bs2f(tw[q].y & 0xffffu), dd1 = bs2f(tw[q].y >> 16);
            float xx = bs2f(xv[q] & 0xffffu), xy = bs2f(xv[q] >> 16);
            ax = fmaf(xx, fmaf(f, dd0, w0), ax);
            ay = fmaf(xy, fmaf(f, dd1, w1), ay);
        }
    }
    for (; e < e1; e++) {
        int2 ed = csr[e];
        unsigned int px = (unsigned int)ed.x;
        uint2 tw = Tb[(px >> 15) * 64 + lane];
        unsigned int xv = xfb[(px & 0x7fffu) * 64 + lane];
        float f = __int_as_float(ed.y);
        float w0 = bs2f(tw.x & 0xffffu), dd0 = bs2f(tw.x >> 16);
        float w1 = bs2f(tw.y & 0xffffu), dd1 = bs2f(tw.y >> 16);
        float xx = bs2f(xv & 0xffffu), xy = bs2f(xv >> 16);
        ax = fmaf(xx, fmaf(f, dd0, w0), ax);
        ay = fmaf(xy, fmaf(f, dd1, w1), ay);
    }
    float2 r; r.x = ax; r.y = ay;
    ((float2*)agg)[(size_t)n * 64 + lane] = r;
}

// parallel mean readout: run-accumulate chunks with atomic flush, then divide
#define RCHUNK 79
__global__ void raccum(const float* __restrict__ hout, const int* __restrict__ batch,
                       float* __restrict__ out) {
    int b = blockIdx.x, c = threadIdx.x;
    int n0 = b * RCHUNK;
    if (n0 >= NN) return;
    int n1 = n0 + RCHUNK; if (n1 > NN) n1 = NN;
    int g = batch[n0];
    float s = 0.f;
    for (int n = n0; n < n1; n++) {
        int bg = batch[n];
        if (bg != g) { atomicAdd(&out[g * 128 + c], s); s = 0.f; g = bg; }
        s += hout[(size_t)n * 128 + c];
    }
    atomicAdd(&out[g * 128 + c], s);
}

__global__ void rdiv(const int* __restrict__ batch, float* __restrict__ out) {
    int g = blockIdx.x;
    int c = threadIdx.x;
    __shared__ int sh[2];
    if (c < 2) {
        int target = g + c;
        int lo = 0, hi = NN;
        while (lo < hi) {
            int mid = (lo + hi) >> 1;
            if (batch[mid] < target) lo = mid + 1; else hi = mid;
        }
        sh[c] = lo;
    }
    __syncthreads();
    int cnt = sh[1] - sh[0];
    out[g * 128 + c] /= (float)(cnt > 0 ? cnt : 1);
}

extern "C" void kernel_launch(void* const* d_in, const int* in_sizes, int n_in,
                              void* d_out, int out_size, void* d_ws, size_t ws_size,
                              hipStream_t stream) {
    const int*   z       = (const int*)d_in[0];
    const float* pos     = (const float*)d_in[1];
    const int*   eidx    = (const int*)d_in[2];
    const int*   src     = eidx;
    const int*   dst     = eidx + NE;
    const int*   batch   = (const int*)d_in[3];
    const float* emb     = (const float*)d_in[4];
    const float* mlp_w1  = (const float*)d_in[5];
    const float* mlp_b1  = (const float*)d_in[6];
    const float* mlp_w2  = (const float*)d_in[7];
    const float* mlp_b2  = (const float*)d_in[8];
    const float* conv_w1 = (const float*)d_in[9];
    const float* conv_w2 = (const float*)d_in[10];
    const float* conv_b2 = (const float*)d_in[11];
    const float* lin_w   = (const float*)d_in[12];
    const float* lin_b   = (const float*)d_in[13];
    const float* out1_w  = (const float*)d_in[14];
    const float* out1_b  = (const float*)d_in[15];
    const float* out2_w  = (const float*)d_in[16];
    const float* out2_b  = (const float*)d_in[17];
    float* out = (float*)d_out;

    char* wp = (char*)d_ws;
    auto alloc = [&](size_t bytes) {
        char* p = wp;
        wp += (bytes + 255) & ~(size_t)255;
        return p;
    };
    const int Mt = TBL + 2;
    int*    deg     = (int*)alloc(NN * 4);
    int*    row_ptr = (int*)alloc((NN + 1) * 4);
    int*    cursor  = (int*)alloc(NN * 4);
    int2*   csr     = (int2*)alloc((size_t)NE * 8);
    float*  A_tab   = (float*)alloc((size_t)Mt * GDIM * 4);
    float*  T1all   = (float*)alloc((size_t)LAYERS * Mt * 128 * 4);
    float*  T       = (float*)alloc((size_t)LAYERS * Mt * 128 * 4);
    uint2*  Tb      = (uint2*)alloc((size_t)LAYERS * (TBL + 1) * 64 * 8);
    float*  h       = (float*)alloc((size_t)NN * 128 * 4);
    float*  agg     = (float*)alloc((size_t)NN * 128 * 4);
    unsigned short* xfb = (unsigned short*)alloc((size_t)NN * 128 * 2);
    unsigned short* wbf = (unsigned short*)alloc((size_t)26 * 16384 * 2);
    unsigned short* mlp_w2t  = wbf;
    unsigned short* conv_w1t = wbf + (size_t)6 * 16384;
    unsigned short* conv_w2t = wbf + (size_t)12 * 16384;
    unsigned short* lin_wt   = wbf + (size_t)18 * 16384;
    unsigned short* out1_wt  = wbf + (size_t)24 * 16384;
    unsigned short* out2_wt  = wbf + (size_t)25 * 16384;

    // init (deg=0, out=0, gaussian attr table)
    const int initN = NN + NGRAPH * 128 + Mt * GDIM;
    init_misc<<<(initN + 255) / 256, 256, 0, stream>>>(deg, out, A_tab);

    // graph structure
    deg_hist<<<(NE + 255) / 256, 256, 0, stream>>>(dst, deg);
    scan_deg<<<1, 1024, 0, stream>>>(deg, row_ptr, cursor);
    csr_fill<<<(NE + 255) / 256, 256, 0, stream>>>(pos, src, dst, cursor, csr);

    // all weight transposes in one launch
    WArgs wa;
    for (int l = 0; l < 6; l++) {
        wa.s[l]      = mlp_w2  + (size_t)l * 16384;  wa.d[l]      = mlp_w2t  + (size_t)l * 16384;
        wa.s[6 + l]  = conv_w1 + (size_t)l * 16384;  wa.d[6 + l]  = conv_w1t + (size_t)l * 16384;
        wa.s[12 + l] = conv_w2 + (size_t)l * 16384;  wa.d[12 + l] = conv_w2t + (size_t)l * 16384;
        wa.s[18 + l] = lin_w   + (size_t)l * 16384;  wa.d[18 + l] = lin_wt   + (size_t)l * 16384;
    }
    wa.s[24] = out1_w; wa.d[24] = out1_wt;
    wa.s[25] = out2_w; wa.d[25] = out2_wt;
    wprep_all<<<dim3(4, 4, 26), 256, 0, stream>>>(wa);

    // filter tables
    const int gt32 = (Mt + 31) / 32;
    gemm_t<GDIM><<<dim3(gt32, LAYERS), 256, 0, stream>>>(
        A_tab, mlp_w1, mlp_b1, T1all, Mt, 1, 0, GDIM * 128, 128, Mt * 128);
    const int gtb = (Mt + 127) / 128;
    gemm_mfma32<<<dim3(gtb, LAYERS), 256, 0, stream>>>(
        T1all, mlp_w2t, mlp_b2, nullptr, T, nullptr, Mt, 0,
        Mt * 128, 16384, 128, Mt * 128);
    tquant<<<(LAYERS * (TBL + 1) * 64 + 255) / 256, 256, 0, stream>>>(T, Tb);

    // node embedding
    h_init<<<(NN * 32 + 255) / 256, 256, 0, stream>>>(z, emb, h);

    const int gn = (NN + 127) / 128;   // 157 blocks
    for (int l = 0; l < LAYERS; l++) {
        // xf(bf16) = h @ conv_w1[l]
        gemm_mfma32<<<gn, 256, 0, stream>>>(h, conv_w1t + (size_t)l * 16384,
                                            nullptr, nullptr, nullptr, xfb, NN, 0, 0, 0, 0, 0);
        edge_agg<<<(NN + 3) / 4, 256, 0, stream>>>(row_ptr, csr,
                                                   Tb + (size_t)l * (TBL + 1) * 64,
                                                   (const unsigned int*)xfb, agg);
        // h = h + ssp(agg @ conv_w2[l] + b2) @ lin_w[l] + lin_b[l]   (fused)
        gemm2<<<gn, 256, 0, stream>>>(agg, conv_w2t + (size_t)l * 16384, conv_b2 + l * 128,
                                      lin_wt + (size_t)l * 16384, lin_b + l * 128,
                                      h, h, NN);
    }

    // output head (fused): hout = ssp(h @ out1 + b1) @ out2 + b2
    gemm2<<<gn, 256, 0, stream>>>(h, out1_wt, out1_b, out2_wt, out2_b,
                                  nullptr, agg, NN);

    // per-graph mean
    raccum<<<(NN + RCHUNK - 1) / RCHUNK, 128, 0, stream>>>(agg, batch, out);
    rdiv<<<NGRAPH, 128, 0, stream>>>(batch, out);
}

// Round 5
// 712.134 us; speedup vs baseline: 2.2996x; 1.4527x over previous
//
#include <hip/hip_runtime.h>
#include <math.h>

#define NN 20000
#define NE 640000
#define GDIM 50
#define LAYERS 6
#define NGRAPH 64
#define TBL 2048
#define DMAXF 12.8f
#define G2_PAD 136   // LDS row stride in shorts (128 + 8 pad)

typedef __attribute__((ext_vector_type(8))) short short8;
typedef __attribute__((ext_vector_type(4))) float floatx4;

__device__ __forceinline__ float sspf(float x) {
    float sp = (x > 30.0f) ? x : log1pf(expf(x));
    return sp - 0.69314718055994530942f;
}

__device__ __forceinline__ unsigned short f2bs(float f) {
    union { float f; unsigned int i; } u; u.f = f;
    unsigned int r = u.i + 0x7fffu + ((u.i >> 16) & 1u);
    return (unsigned short)(r >> 16);
}

__device__ __forceinline__ float bs2f(unsigned int bits16) {
    union { unsigned int i; float f; } u; u.i = bits16 << 16;
    return u.f;
}

__device__ __forceinline__ short8 pack_bf16x8(float4 a, float4 b) {
    short8 o;
    o[0] = (short)f2bs(a.x); o[1] = (short)f2bs(a.y);
    o[2] = (short)f2bs(a.z); o[3] = (short)f2bs(a.w);
    o[4] = (short)f2bs(b.x); o[5] = (short)f2bs(b.y);
    o[6] = (short)f2bs(b.z); o[7] = (short)f2bs(b.w);
    return o;
}

// zero deg + zero out + fill gaussian attr table, one launch
__global__ void init_misc(int* __restrict__ deg, float* __restrict__ out,
                          float* __restrict__ A) {
    int idx = blockIdx.x * blockDim.x + threadIdx.x;
    if (idx < NN) { deg[idx] = 0; return; }
    int j = idx - NN;
    if (j < NGRAPH * 128) { out[j] = 0.f; return; }
    j -= NGRAPH * 128;
    const int total = (TBL + 2) * GDIM;
    if (j >= total) return;
    int i = j / GDIM, g = j % GDIM;
    float v = 0.0f;
    if (i <= TBL) {
        float d = (float)i * (DMAXF / (float)TBL);
        float step = 10.0f / 49.0f;
        float off = (float)g * step;
        float coeff = -0.5f / (step * step);
        float dd = d - off;
        v = expf(coeff * dd * dd);
    }
    A[j] = v;
}

__global__ void deg_hist(const int* __restrict__ dst, int* __restrict__ deg) {
    int j = blockIdx.x * blockDim.x + threadIdx.x;
    if (j >= NE) return;
    atomicAdd(&deg[dst[j]], 1);
}

__global__ void scan_deg(const int* __restrict__ deg, int* __restrict__ row_ptr,
                         int* __restrict__ cursor) {
    __shared__ int part[1024];
    const int n = NN;
    const int PER = 20;
    int t = threadIdx.x;
    int base = t * PER;
    int local[PER];
    int s = 0;
    #pragma unroll
    for (int i = 0; i < PER; i++) {
        int k = base + i;
        local[i] = s;
        if (k < n) s += deg[k];
    }
    part[t] = s;
    __syncthreads();
    for (int off = 1; off < 1024; off <<= 1) {
        int v = (t >= off) ? part[t - off] : 0;
        __syncthreads();
        part[t] += v;
        __syncthreads();
    }
    int offset = (t > 0) ? part[t - 1] : 0;
    #pragma unroll
    for (int i = 0; i < PER; i++) {
        int k = base + i;
        if (k <= n) {
            int v = offset + local[i];
            row_ptr[k] = v;
            if (k < n) cursor[k] = v;
        }
    }
}

// CSR entry: int2{ (i0<<15)|src , bits(f) }   (cutoff C folded into table)
__global__ void csr_fill(const float* __restrict__ pos, const int* __restrict__ src,
                         const int* __restrict__ dst, int* __restrict__ cursor,
                         int2* __restrict__ csr) {
    int j = blockIdx.x * blockDim.x + threadIdx.x;
    if (j >= NE) return;
    int s = src[j], tno = dst[j];
    float dx = pos[3*s+0] - pos[3*tno+0];
    float dy = pos[3*s+1] - pos[3*tno+1];
    float dz = pos[3*s+2] - pos[3*tno+2];
    float d = sqrtf(dx*dx + dy*dy + dz*dz);
    float u = d * ((float)TBL / DMAXF);
    u = fminf(u, (float)(TBL + 1));
    int i0 = (int)u; if (i0 > TBL) i0 = TBL;
    float f = u - (float)i0;
    int p = atomicAdd(&cursor[tno], 1);
    csr[p] = make_int2((i0 << 15) | s, __float_as_int(f));
}

// fp32 tiled GEMM for the K=50 table stage only, batched over gridDim.y
template <int K>
__launch_bounds__(256, 2)
__global__ void gemm_t(const float* __restrict__ A, const float* __restrict__ W,
                       const float* __restrict__ bias, float* __restrict__ Y, int M,
                       int act, int aStride, int wStride, int bStride, int yStride) {
    constexpr int KP = (K + 3) & ~3;
    __shared__ __align__(16) float Ws[KP * 128];
    __shared__ __align__(16) float As[32 * KP];
    int l = blockIdx.y;
    A += (size_t)l * aStride;
    W += (size_t)l * wStride;
    if (bias) bias += (size_t)l * bStride;
    Y += (size_t)l * yStride;
    int t = threadIdx.x;
    int row0 = blockIdx.x * 32;
    for (int i = t; i < KP * 128; i += 256) Ws[i] = (i < K * 128) ? W[i] : 0.0f;
    for (int i = t; i < 32 * KP; i += 256) {
        int r = i / KP, k = i % KP;
        float v = 0.f;
        if (k < K && row0 + r < M) v = A[(size_t)(row0 + r) * K + k];
        As[r * KP + k] = v;
    }
    __syncthreads();
    int tx = t & 31, ty = t >> 5;
    int c0 = tx * 4, r0 = ty * 4;
    float acc[4][4] = {{0.f}};
    #pragma unroll 4
    for (int k = 0; k < KP; k += 4) {
        float4 a0 = *(const float4*)&As[(r0 + 0) * KP + k];
        float4 a1 = *(const float4*)&As[(r0 + 1) * KP + k];
        float4 a2 = *(const float4*)&As[(r0 + 2) * KP + k];
        float4 a3 = *(const float4*)&As[(r0 + 3) * KP + k];
        float4 w0 = *(const float4*)&Ws[(k + 0) * 128 + c0];
        float4 w1 = *(const float4*)&Ws[(k + 1) * 128 + c0];
        float4 w2 = *(const float4*)&Ws[(k + 2) * 128 + c0];
        float4 w3 = *(const float4*)&Ws[(k + 3) * 128 + c0];
        float av[4][4] = {{a0.x,a0.y,a0.z,a0.w},{a1.x,a1.y,a1.z,a1.w},
                          {a2.x,a2.y,a2.z,a2.w},{a3.x,a3.y,a3.z,a3.w}};
        float wv[4][4] = {{w0.x,w0.y,w0.z,w0.w},{w1.x,w1.y,w1.z,w1.w},
                          {w2.x,w2.y,w2.z,w2.w},{w3.x,w3.y,w3.z,w3.w}};
        #pragma unroll
        for (int i = 0; i < 4; i++)
            #pragma unroll
            for (int j = 0; j < 4; j++)
                #pragma unroll
                for (int q = 0; q < 4; q++)
                    acc[i][j] += av[i][q] * wv[q][j];
    }
    float b0 = 0.f, b1 = 0.f, b2 = 0.f, b3 = 0.f;
    if (bias) { b0 = bias[c0]; b1 = bias[c0+1]; b2 = bias[c0+2]; b3 = bias[c0+3]; }
    #pragma unroll
    for (int i = 0; i < 4; i++) {
        int r = row0 + r0 + i;
        if (r >= M) break;
        float4 v;
        v.x = acc[i][0] + b0; v.y = acc[i][1] + b1; v.z = acc[i][2] + b2; v.w = acc[i][3] + b3;
        if (act == 1) { v.x = sspf(v.x); v.y = sspf(v.y); v.z = sspf(v.z); v.w = sspf(v.w); }
        *(float4*)&Y[(size_t)r * 128 + c0] = v;
    }
}

// batched transpose + bf16 quantize of all 26 weight matrices in one launch
struct WArgs { const float* s[26]; unsigned short* d[26]; };
__global__ void wprep_all(WArgs a) {
    __shared__ float tile[32][33];
    int mz = blockIdx.z;
    const float* Wm = a.s[mz];
    unsigned short* Wo = a.d[mz];
    int bx = blockIdx.x * 32, by = blockIdx.y * 32;
    int tx = threadIdx.x & 31, ty = threadIdx.x >> 5;
    for (int r = ty; r < 32; r += 8) tile[r][tx] = Wm[(by + r) * 128 + bx + tx];
    __syncthreads();
    for (int r = ty; r < 32; r += 8) Wo[(bx + r) * 128 + by + tx] = f2bs(tile[tx][r]);
}

// column-split bf16 MFMA GEMM: block = 32 rows, wave w computes cols [32w,32w+32)
// Y = act(A[M,128] @ Wt^T + bias); batched over gridDim.y
__launch_bounds__(256)
__global__ void gemm_cs(const float* __restrict__ A, const unsigned short* __restrict__ Wt,
                        const float* __restrict__ bias,
                        float* __restrict__ Yf, unsigned short* __restrict__ Yb,
                        int M, int act,
                        int aStride, int wStride, int bStride, int yStride) {
    int l = blockIdx.y;
    A += (size_t)l * aStride;
    Wt += (size_t)l * wStride;
    if (bias) bias += (size_t)l * bStride;
    if (Yf) Yf += (size_t)l * yStride;
    if (Yb) Yb += (size_t)l * yStride;
    int wv = threadIdx.x >> 6, lane = threadIdx.x & 63;
    int row0 = blockIdx.x * 32;
    if (row0 >= M) return;
    int lm = lane & 15, lk = (lane >> 4) * 8, orow = (lane >> 4) * 4;
    int r0 = row0 + lm;      r0 = (r0 < M) ? r0 : M - 1;
    int r1 = row0 + 16 + lm; r1 = (r1 < M) ? r1 : M - 1;
    const float* Ap0 = A + (size_t)r0 * 128;
    const float* Ap1 = A + (size_t)r1 * 128;
    short8 af0[4], af1[4];
    #pragma unroll
    for (int kq = 0; kq < 4; kq++) {
        af0[kq] = pack_bf16x8(*(const float4*)(Ap0 + kq * 32 + lk),
                              *(const float4*)(Ap0 + kq * 32 + lk + 4));
        af1[kq] = pack_bf16x8(*(const float4*)(Ap1 + kq * 32 + lk),
                              *(const float4*)(Ap1 + kq * 32 + lk + 4));
    }
    floatx4 acc[2][2];
    #pragma unroll
    for (int i = 0; i < 2; i++)
        #pragma unroll
        for (int j = 0; j < 2; j++) acc[i][j] = (floatx4){0, 0, 0, 0};
    const unsigned short* Wp = Wt + (size_t)(wv * 32) * 128;
    #pragma unroll
    for (int kq = 0; kq < 4; kq++) {
        #pragma unroll
        for (int ct = 0; ct < 2; ct++) {
            short8 bf = *(const short8*)(Wp + (size_t)(ct * 16 + lm) * 128 + kq * 32 + lk);
            acc[0][ct] = __builtin_amdgcn_mfma_f32_16x16x32_bf16(af0[kq], bf, acc[0][ct], 0, 0, 0);
            acc[1][ct] = __builtin_amdgcn_mfma_f32_16x16x32_bf16(af1[kq], bf, acc[1][ct], 0, 0, 0);
        }
    }
    #pragma unroll
    for (int tt = 0; tt < 2; tt++) {
        #pragma unroll
        for (int ct = 0; ct < 2; ct++) {
            int c = wv * 32 + ct * 16 + lm;
            float b = bias ? bias[c] : 0.f;
            #pragma unroll
            for (int r = 0; r < 4; r++) {
                int rr = row0 + tt * 16 + orow + r;
                if (rr >= M) continue;
                float v = acc[tt][ct][r] + b;
                if (act) v = sspf(v);
                if (Yf) Yf[(size_t)rr * 128 + c] = v;
                if (Yb) Yb[(size_t)rr * 128 + c] = f2bs(v);
            }
        }
    }
}

// fused triple GEMM (the per-layer workhorse), 32 rows/block, col-split waves:
//   t1    = ssp(A @ W2t^T + b2)            (LDS round-trip, bf16)
//   h_new = t1 @ W3t^T + b3 [+ resid]  -> Yf (fp32)
//   xfb   = bf16(h_new @ W1nt^T)       -> xfb (if W1nt != null)
// Requires M % 32 == 0 (NN = 20000 = 625*32).
__launch_bounds__(256)
__global__ void gemm3(const float* __restrict__ A,
                      const unsigned short* __restrict__ W2t, const float* __restrict__ b2,
                      const unsigned short* __restrict__ W3t, const float* __restrict__ b3,
                      const float* __restrict__ resid, float* __restrict__ Yf,
                      const unsigned short* __restrict__ W1nt, unsigned short* __restrict__ xfb) {
    __shared__ unsigned short Ls[32 * G2_PAD];
    int wv = threadIdx.x >> 6, lane = threadIdx.x & 63;
    int row0 = blockIdx.x * 32;
    int lm = lane & 15, lk = (lane >> 4) * 8, orow = (lane >> 4) * 4;
    int cw = wv * 32;
    // ---- phase 1: t1 = ssp(A @ W2t^T + b2) -> LDS ----
    {
        const float* Ap0 = A + (size_t)(row0 + lm) * 128;
        const float* Ap1 = A + (size_t)(row0 + 16 + lm) * 128;
        short8 af0[4], af1[4];
        #pragma unroll
        for (int kq = 0; kq < 4; kq++) {
            af0[kq] = pack_bf16x8(*(const float4*)(Ap0 + kq * 32 + lk),
                                  *(const float4*)(Ap0 + kq * 32 + lk + 4));
            af1[kq] = pack_bf16x8(*(const float4*)(Ap1 + kq * 32 + lk),
                                  *(const float4*)(Ap1 + kq * 32 + lk + 4));
        }
        floatx4 acc[2][2];
        #pragma unroll
        for (int i = 0; i < 2; i++)
            #pragma unroll
            for (int j = 0; j < 2; j++) acc[i][j] = (floatx4){0, 0, 0, 0};
        const unsigned short* Wp = W2t + (size_t)cw * 128;
        #pragma unroll
        for (int kq = 0; kq < 4; kq++) {
            #pragma unroll
            for (int ct = 0; ct < 2; ct++) {
                short8 bf = *(const short8*)(Wp + (size_t)(ct * 16 + lm) * 128 + kq * 32 + lk);
                acc[0][ct] = __builtin_amdgcn_mfma_f32_16x16x32_bf16(af0[kq], bf, acc[0][ct], 0, 0, 0);
                acc[1][ct] = __builtin_amdgcn_mfma_f32_16x16x32_bf16(af1[kq], bf, acc[1][ct], 0, 0, 0);
            }
        }
        #pragma unroll
        for (int tt = 0; tt < 2; tt++)
            #pragma unroll
            for (int ct = 0; ct < 2; ct++) {
                int c = cw + ct * 16 + lm;
                float b = b2[c];
                #pragma unroll
                for (int r = 0; r < 4; r++)
                    Ls[(tt * 16 + orow + r) * G2_PAD + c] = f2bs(sspf(acc[tt][ct][r] + b));
            }
    }
    __syncthreads();
    // ---- phase 2: h_new = t1 @ W3t^T + b3 [+resid] -> Yf ----
    float vout[2][2][4];
    {
        short8 a0[4], a1[4];
        #pragma unroll
        for (int kq = 0; kq < 4; kq++) {
            a0[kq] = *(const short8*)&Ls[lm * G2_PAD + kq * 32 + lk];
            a1[kq] = *(const short8*)&Ls[(16 + lm) * G2_PAD + kq * 32 + lk];
        }
        floatx4 acc[2][2];
        #pragma unroll
        for (int i = 0; i < 2; i++)
            #pragma unroll
            for (int j = 0; j < 2; j++) acc[i][j] = (floatx4){0, 0, 0, 0};
        const unsigned short* Wp = W3t + (size_t)cw * 128;
        #pragma unroll
        for (int kq = 0; kq < 4; kq++) {
            #pragma unroll
            for (int ct = 0; ct < 2; ct++) {
                short8 bf = *(const short8*)(Wp + (size_t)(ct * 16 + lm) * 128 + kq * 32 + lk);
                acc[0][ct] = __builtin_amdgcn_mfma_f32_16x16x32_bf16(a0[kq], bf, acc[0][ct], 0, 0, 0);
                acc[1][ct] = __builtin_amdgcn_mfma_f32_16x16x32_bf16(a1[kq], bf, acc[1][ct], 0, 0, 0);
            }
        }
        #pragma unroll
        for (int tt = 0; tt < 2; tt++)
            #pragma unroll
            for (int ct = 0; ct < 2; ct++) {
                int c = cw + ct * 16 + lm;
                float b = b3[c];
                #pragma unroll
                for (int r = 0; r < 4; r++) {
                    int rr = row0 + tt * 16 + orow + r;
                    float v = acc[tt][ct][r] + b;
                    if (resid) v += resid[(size_t)rr * 128 + c];
                    Yf[(size_t)rr * 128 + c] = v;
                    vout[tt][ct][r] = v;
                }
            }
    }
    if (!W1nt) return;
    __syncthreads();
    // stash h_new (bf16) into LDS for phase 3
    #pragma unroll
    for (int tt = 0; tt < 2; tt++)
        #pragma unroll
        for (int ct = 0; ct < 2; ct++) {
            int c = cw + ct * 16 + lm;
            #pragma unroll
            for (int r = 0; r < 4; r++)
                Ls[(tt * 16 + orow + r) * G2_PAD + c] = f2bs(vout[tt][ct][r]);
        }
    __syncthreads();
    // ---- phase 3: xfb = bf16(h_new @ W1nt^T) ----
    {
        short8 a0[4], a1[4];
        #pragma unroll
        for (int kq = 0; kq < 4; kq++) {
            a0[kq] = *(const short8*)&Ls[lm * G2_PAD + kq * 32 + lk];
            a1[kq] = *(const short8*)&Ls[(16 + lm) * G2_PAD + kq * 32 + lk];
        }
        floatx4 acc[2][2];
        #pragma unroll
        for (int i = 0; i < 2; i++)
            #pragma unroll
            for (int j = 0; j < 2; j++) acc[i][j] = (floatx4){0, 0, 0, 0};
        const unsigned short* Wp = W1nt + (size_t)cw * 128;
        #pragma unroll
        for (int kq = 0; kq < 4; kq++) {
            #pragma unroll
            for (int ct = 0; ct < 2; ct++) {
                short8 bf = *(const short8*)(Wp + (size_t)(ct * 16 + lm) * 128 + kq * 32 + lk);
                acc[0][ct] = __builtin_amdgcn_mfma_f32_16x16x32_bf16(a0[kq], bf, acc[0][ct], 0, 0, 0);
                acc[1][ct] = __builtin_amdgcn_mfma_f32_16x16x32_bf16(a1[kq], bf, acc[1][ct], 0, 0, 0);
            }
        }
        #pragma unroll
        for (int tt = 0; tt < 2; tt++)
            #pragma unroll
            for (int ct = 0; ct < 2; ct++) {
                int c = cw + ct * 16 + lm;
                #pragma unroll
                for (int r = 0; r < 4; r++) {
                    int rr = row0 + tt * 16 + orow + r;
                    xfb[(size_t)rr * 128 + c] = f2bs(acc[tt][ct][r]);
                }
            }
    }
}

// fold cutoff C(d) into table; store interleaved (T', dT') bf16 pairs per channel pair
__global__ void tquant(const float* __restrict__ T, uint2* __restrict__ Tb) {
    int idx = blockIdx.x * blockDim.x + threadIdx.x;
    const int total = LAYERS * (TBL + 1) * 64;
    if (idx >= total) return;
    int lane = idx & 63;
    int li = idx >> 6;
    int i = li % (TBL + 1);
    int l = li / (TBL + 1);
    float d0 = (float)i * (DMAXF / (float)TBL);
    float d1 = (float)(i + 1) * (DMAXF / (float)TBL);
    float C0 = 0.5f * (cosf(d0 * 0.31415926535897931f) + 1.0f);
    float C1 = 0.5f * (cosf(d1 * 0.31415926535897931f) + 1.0f);
    const float* row = T + ((size_t)l * (TBL + 2) + i) * 128 + lane * 2;
    float w0 = row[0] * C0,   w1 = row[1] * C0;
    float n0 = row[128] * C1, n1 = row[129] * C1;
    uint2 o;
    o.x = ((unsigned)f2bs(n0 - w0) << 16) | f2bs(w0);
    o.y = ((unsigned)f2bs(n1 - w1) << 16) | f2bs(w1);
    Tb[idx] = o;
}

__global__ void h_init(const int* __restrict__ z, const float* __restrict__ emb,
                       float* __restrict__ h) {
    int idx = blockIdx.x * blockDim.x + threadIdx.x;
    if (idx >= NN * 32) return;
    int n = idx >> 5, q = idx & 31;
    ((float4*)h)[n * 32 + q] = ((const float4*)emb)[z[n] * 32 + q];
}

// one wave per node: agg = sum_e xfb[src] * (T'[i0] + f*dT')
__launch_bounds__(256)
__global__ void edge_agg(const int* __restrict__ row_ptr, const int2* __restrict__ csr,
                         const uint2* __restrict__ Tb, const unsigned int* __restrict__ xfb,
                         float* __restrict__ agg) {
    int wave = threadIdx.x >> 6;
    int lane = threadIdx.x & 63;
    int n = blockIdx.x * 4 + wave;
    if (n >= NN) return;
    int e0 = row_ptr[n], e1 = row_ptr[n + 1];
    float ax = 0.f, ay = 0.f;
    int e = e0;
    for (; e + 8 <= e1; e += 8) {
        int2 ed[8]; uint2 tw[8]; unsigned int xv[8];
        #pragma unroll
        for (int q = 0; q < 8; q++) ed[q] = csr[e + q];
        #pragma unroll
        for (int q = 0; q < 8; q++) {
            unsigned int px = (unsigned int)ed[q].x;
            tw[q] = Tb[(px >> 15) * 64 + lane];
            xv[q] = xfb[(px & 0x7fffu) * 64 + lane];
        }
        #pragma unroll
        for (int q = 0; q < 8; q++) {
            float f = __int_as_float(ed[q].y);
            float w0 = bs2f(tw[q].x & 0xffffu), dd0 = bs2f(tw[q].x >> 16);
            float w1 = bs2f(tw[q].y & 0xffffu), dd1 = bs2f(tw[q].y >> 16);
            float xx = bs2f(xv[q] & 0xffffu), xy = bs2f(xv[q] >> 16);
            ax = fmaf(xx, fmaf(f, dd0, w0), ax);
            ay = fmaf(xy, fmaf(f, dd1, w1), ay);
        }
    }
    for (; e < e1; e++) {
        int2 ed = csr[e];
        unsigned int px = (unsigned int)ed.x;
        uint2 tw = Tb[(px >> 15) * 64 + lane];
        unsigned int xv = xfb[(px & 0x7fffu) * 64 + lane];
        float f = __int_as_float(ed.y);
        float w0 = bs2f(tw.x & 0xffffu), dd0 = bs2f(tw.x >> 16);
        float w1 = bs2f(tw.y & 0xffffu), dd1 = bs2f(tw.y >> 16);
        float xx = bs2f(xv & 0xffffu), xy = bs2f(xv >> 16);
        ax = fmaf(xx, fmaf(f, dd0, w0), ax);
        ay = fmaf(xy, fmaf(f, dd1, w1), ay);
    }
    float2 r; r.x = ax; r.y = ay;
    ((float2*)agg)[(size_t)n * 64 + lane] = r;
}

// parallel mean readout: run-accumulate chunks with atomic flush, then divide
#define RCHUNK 79
__global__ void raccum(const float* __restrict__ hout, const int* __restrict__ batch,
                       float* __restrict__ out) {
    int b = blockIdx.x, c = threadIdx.x;
    int n0 = b * RCHUNK;
    if (n0 >= NN) return;
    int n1 = n0 + RCHUNK; if (n1 > NN) n1 = NN;
    int g = batch[n0];
    float s = 0.f;
    for (int n = n0; n < n1; n++) {
        int bg = batch[n];
        if (bg != g) { atomicAdd(&out[g * 128 + c], s); s = 0.f; g = bg; }
        s += hout[(size_t)n * 128 + c];
    }
    atomicAdd(&out[g * 128 + c], s);
}

__global__ void rdiv(const int* __restrict__ batch, float* __restrict__ out) {
    int g = blockIdx.x;
    int c = threadIdx.x;
    __shared__ int sh[2];
    if (c < 2) {
        int target = g + c;
        int lo = 0, hi = NN;
        while (lo < hi) {
            int mid = (lo + hi) >> 1;
            if (batch[mid] < target) lo = mid + 1; else hi = mid;
        }
        sh[c] = lo;
    }
    __syncthreads();
    int cnt = sh[1] - sh[0];
    out[g * 128 + c] /= (float)(cnt > 0 ? cnt : 1);
}

extern "C" void kernel_launch(void* const* d_in, const int* in_sizes, int n_in,
                              void* d_out, int out_size, void* d_ws, size_t ws_size,
                              hipStream_t stream) {
    const int*   z       = (const int*)d_in[0];
    const float* pos     = (const float*)d_in[1];
    const int*   eidx    = (const int*)d_in[2];
    const int*   src     = eidx;
    const int*   dst     = eidx + NE;
    const int*   batch   = (const int*)d_in[3];
    const float* emb     = (const float*)d_in[4];
    const float* mlp_w1  = (const float*)d_in[5];
    const float* mlp_b1  = (const float*)d_in[6];
    const float* mlp_w2  = (const float*)d_in[7];
    const float* mlp_b2  = (const float*)d_in[8];
    const float* conv_w1 = (const float*)d_in[9];
    const float* conv_w2 = (const float*)d_in[10];
    const float* conv_b2 = (const float*)d_in[11];
    const float* lin_w   = (const float*)d_in[12];
    const float* lin_b   = (const float*)d_in[13];
    const float* out1_w  = (const float*)d_in[14];
    const float* out1_b  = (const float*)d_in[15];
    const float* out2_w  = (const float*)d_in[16];
    const float* out2_b  = (const float*)d_in[17];
    float* out = (float*)d_out;

    char* wp = (char*)d_ws;
    auto alloc = [&](size_t bytes) {
        char* p = wp;
        wp += (bytes + 255) & ~(size_t)255;
        return p;
    };
    const int Mt = TBL + 2;
    int*    deg     = (int*)alloc(NN * 4);
    int*    row_ptr = (int*)alloc((NN + 1) * 4);
    int*    cursor  = (int*)alloc(NN * 4);
    int2*   csr     = (int2*)alloc((size_t)NE * 8);
    float*  A_tab   = (float*)alloc((size_t)Mt * GDIM * 4);
    float*  T1all   = (float*)alloc((size_t)LAYERS * Mt * 128 * 4);
    float*  T       = (float*)alloc((size_t)LAYERS * Mt * 128 * 4);
    uint2*  Tb      = (uint2*)alloc((size_t)LAYERS * (TBL + 1) * 64 * 8);
    float*  h       = (float*)alloc((size_t)NN * 128 * 4);
    float*  agg     = (float*)alloc((size_t)NN * 128 * 4);
    unsigned short* xfb = (unsigned short*)alloc((size_t)NN * 128 * 2);
    unsigned short* wbf = (unsigned short*)alloc((size_t)26 * 16384 * 2);
    unsigned short* mlp_w2t  = wbf;
    unsigned short* conv_w1t = wbf + (size_t)6 * 16384;
    unsigned short* conv_w2t = wbf + (size_t)12 * 16384;
    unsigned short* lin_wt   = wbf + (size_t)18 * 16384;
    unsigned short* out1_wt  = wbf + (size_t)24 * 16384;
    unsigned short* out2_wt  = wbf + (size_t)25 * 16384;

    // init (deg=0, out=0, gaussian attr table)
    const int initN = NN + NGRAPH * 128 + Mt * GDIM;
    init_misc<<<(initN + 255) / 256, 256, 0, stream>>>(deg, out, A_tab);

    // graph structure
    deg_hist<<<(NE + 255) / 256, 256, 0, stream>>>(dst, deg);
    scan_deg<<<1, 1024, 0, stream>>>(deg, row_ptr, cursor);
    csr_fill<<<(NE + 255) / 256, 256, 0, stream>>>(pos, src, dst, cursor, csr);

    // all weight transposes in one launch
    WArgs wa;
    for (int l = 0; l < 6; l++) {
        wa.s[l]      = mlp_w2  + (size_t)l * 16384;  wa.d[l]      = mlp_w2t  + (size_t)l * 16384;
        wa.s[6 + l]  = conv_w1 + (size_t)l * 16384;  wa.d[6 + l]  = conv_w1t + (size_t)l * 16384;
        wa.s[12 + l] = conv_w2 + (size_t)l * 16384;  wa.d[12 + l] = conv_w2t + (size_t)l * 16384;
        wa.s[18 + l] = lin_w   + (size_t)l * 16384;  wa.d[18 + l] = lin_wt   + (size_t)l * 16384;
    }
    wa.s[24] = out1_w; wa.d[24] = out1_wt;
    wa.s[25] = out2_w; wa.d[25] = out2_wt;
    wprep_all<<<dim3(4, 4, 26), 256, 0, stream>>>(wa);

    // filter tables
    const int gt32 = (Mt + 31) / 32;
    gemm_t<GDIM><<<dim3(gt32, LAYERS), 256, 0, stream>>>(
        A_tab, mlp_w1, mlp_b1, T1all, Mt, 1, 0, GDIM * 128, 128, Mt * 128);
    gemm_cs<<<dim3(gt32, LAYERS), 256, 0, stream>>>(
        T1all, mlp_w2t, mlp_b2, T, nullptr, Mt, 0,
        Mt * 128, 16384, 128, Mt * 128);
    tquant<<<(LAYERS * (TBL + 1) * 64 + 255) / 256, 256, 0, stream>>>(T, Tb);

    // node embedding + layer-0 conv filter input
    h_init<<<(NN * 32 + 255) / 256, 256, 0, stream>>>(z, emb, h);
    const int gn = NN / 32;   // 625, exact
    gemm_cs<<<gn, 256, 0, stream>>>(h, conv_w1t, nullptr, nullptr, xfb, NN, 0, 0, 0, 0, 0);

    for (int l = 0; l < LAYERS; l++) {
        edge_agg<<<(NN + 3) / 4, 256, 0, stream>>>(row_ptr, csr,
                                                   Tb + (size_t)l * (TBL + 1) * 64,
                                                   (const unsigned int*)xfb, agg);
        // h = h + ssp(agg @ conv_w2[l] + b2) @ lin_w[l] + lin_b[l]; xfb = h @ conv_w1[l+1]
        const unsigned short* w1n = (l + 1 < LAYERS) ? conv_w1t + (size_t)(l + 1) * 16384 : nullptr;
        gemm3<<<gn, 256, 0, stream>>>(agg, conv_w2t + (size_t)l * 16384, conv_b2 + l * 128,
                                      lin_wt + (size_t)l * 16384, lin_b + l * 128,
                                      h, h, w1n, xfb);
    }

    // output head (fused): hout = ssp(h @ out1 + b1) @ out2 + b2
    gemm3<<<gn, 256, 0, stream>>>(h, out1_wt, out1_b, out2_wt, out2_b,
                                  nullptr, agg, nullptr, nullptr);

    // per-graph mean
    raccum<<<(NN + RCHUNK - 1) / RCHUNK, 128, 0, stream>>>(agg, batch, out);
    rdiv<<<NGRAPH, 128, 0, stream>>>(batch, out);
}

// Round 6
// 620.977 us; speedup vs baseline: 2.6371x; 1.1468x over previous
//
#include <hip/hip_runtime.h>
#include <math.h>

#define NN 20000
#define NE 640000
#define GDIM 50
#define LAYERS 6
#define NGRAPH 64
#define TBL 2048
#define DMAXF 12.8f
#define G2_PAD 136   // LDS row stride in shorts (128 + 8 pad)

typedef __attribute__((ext_vector_type(8))) short short8;
typedef __attribute__((ext_vector_type(4))) float floatx4;

__device__ __forceinline__ float sspf(float x) {
    float sp = (x > 30.0f) ? x : log1pf(expf(x));
    return sp - 0.69314718055994530942f;
}

__device__ __forceinline__ unsigned short f2bs(float f) {
    union { float f; unsigned int i; } u; u.f = f;
    unsigned int r = u.i + 0x7fffu + ((u.i >> 16) & 1u);
    return (unsigned short)(r >> 16);
}

__device__ __forceinline__ float bs2f(unsigned int bits16) {
    union { unsigned int i; float f; } u; u.i = bits16 << 16;
    return u.f;
}

__device__ __forceinline__ short8 pack_bf16x8(float4 a, float4 b) {
    short8 o;
    o[0] = (short)f2bs(a.x); o[1] = (short)f2bs(a.y);
    o[2] = (short)f2bs(a.z); o[3] = (short)f2bs(a.w);
    o[4] = (short)f2bs(b.x); o[5] = (short)f2bs(b.y);
    o[6] = (short)f2bs(b.z); o[7] = (short)f2bs(b.w);
    return o;
}

// zero deg + zero out + fill gaussian attr table, one launch
__global__ void init_misc(int* __restrict__ deg, float* __restrict__ out,
                          float* __restrict__ A) {
    int idx = blockIdx.x * blockDim.x + threadIdx.x;
    if (idx < NN) { deg[idx] = 0; return; }
    int j = idx - NN;
    if (j < NGRAPH * 128) { out[j] = 0.f; return; }
    j -= NGRAPH * 128;
    const int total = (TBL + 2) * GDIM;
    if (j >= total) return;
    int i = j / GDIM, g = j % GDIM;
    float v = 0.0f;
    if (i <= TBL) {
        float d = (float)i * (DMAXF / (float)TBL);
        float step = 10.0f / 49.0f;
        float off = (float)g * step;
        float coeff = -0.5f / (step * step);
        float dd = d - off;
        v = expf(coeff * dd * dd);
    }
    A[j] = v;
}

__global__ void deg_hist(const int* __restrict__ dst, int* __restrict__ deg) {
    int j = blockIdx.x * blockDim.x + threadIdx.x;
    if (j >= NE) return;
    atomicAdd(&deg[dst[j]], 1);
}

__global__ void scan_deg(const int* __restrict__ deg, int* __restrict__ row_ptr,
                         int* __restrict__ cursor) {
    __shared__ int part[1024];
    const int n = NN;
    const int PER = 20;
    int t = threadIdx.x;
    int base = t * PER;
    int local[PER];
    int s = 0;
    #pragma unroll
    for (int i = 0; i < PER; i++) {
        int k = base + i;
        local[i] = s;
        if (k < n) s += deg[k];
    }
    part[t] = s;
    __syncthreads();
    for (int off = 1; off < 1024; off <<= 1) {
        int v = (t >= off) ? part[t - off] : 0;
        __syncthreads();
        part[t] += v;
        __syncthreads();
    }
    int offset = (t > 0) ? part[t - 1] : 0;
    #pragma unroll
    for (int i = 0; i < PER; i++) {
        int k = base + i;
        if (k <= n) {
            int v = offset + local[i];
            row_ptr[k] = v;
            if (k < n) cursor[k] = v;
        }
    }
}

// CSR entry: int2{ (i0<<15)|src , bits(f) }   (cutoff C folded into table)
__global__ void csr_fill(const float* __restrict__ pos, const int* __restrict__ src,
                         const int* __restrict__ dst, int* __restrict__ cursor,
                         int2* __restrict__ csr) {
    int j = blockIdx.x * blockDim.x + threadIdx.x;
    if (j >= NE) return;
    int s = src[j], tno = dst[j];
    float dx = pos[3*s+0] - pos[3*tno+0];
    float dy = pos[3*s+1] - pos[3*tno+1];
    float dz = pos[3*s+2] - pos[3*tno+2];
    float d = sqrtf(dx*dx + dy*dy + dz*dz);
    float u = d * ((float)TBL / DMAXF);
    u = fminf(u, (float)(TBL + 1));
    int i0 = (int)u; if (i0 > TBL) i0 = TBL;
    float f = u - (float)i0;
    int p = atomicAdd(&cursor[tno], 1);
    csr[p] = make_int2((i0 << 15) | s, __float_as_int(f));
}

// fp32 tiled GEMM for the K=50 table stage only, batched over gridDim.y
template <int K>
__launch_bounds__(256, 2)
__global__ void gemm_t(const float* __restrict__ A, const float* __restrict__ W,
                       const float* __restrict__ bias, float* __restrict__ Y, int M,
                       int act, int aStride, int wStride, int bStride, int yStride) {
    constexpr int KP = (K + 3) & ~3;
    __shared__ __align__(16) float Ws[KP * 128];
    __shared__ __align__(16) float As[32 * KP];
    int l = blockIdx.y;
    A += (size_t)l * aStride;
    W += (size_t)l * wStride;
    if (bias) bias += (size_t)l * bStride;
    Y += (size_t)l * yStride;
    int t = threadIdx.x;
    int row0 = blockIdx.x * 32;
    for (int i = t; i < KP * 128; i += 256) Ws[i] = (i < K * 128) ? W[i] : 0.0f;
    for (int i = t; i < 32 * KP; i += 256) {
        int r = i / KP, k = i % KP;
        float v = 0.f;
        if (k < K && row0 + r < M) v = A[(size_t)(row0 + r) * K + k];
        As[r * KP + k] = v;
    }
    __syncthreads();
    int tx = t & 31, ty = t >> 5;
    int c0 = tx * 4, r0 = ty * 4;
    float acc[4][4] = {{0.f}};
    #pragma unroll 4
    for (int k = 0; k < KP; k += 4) {
        float4 a0 = *(const float4*)&As[(r0 + 0) * KP + k];
        float4 a1 = *(const float4*)&As[(r0 + 1) * KP + k];
        float4 a2 = *(const float4*)&As[(r0 + 2) * KP + k];
        float4 a3 = *(const float4*)&As[(r0 + 3) * KP + k];
        float4 w0 = *(const float4*)&Ws[(k + 0) * 128 + c0];
        float4 w1 = *(const float4*)&Ws[(k + 1) * 128 + c0];
        float4 w2 = *(const float4*)&Ws[(k + 2) * 128 + c0];
        float4 w3 = *(const float4*)&Ws[(k + 3) * 128 + c0];
        float av[4][4] = {{a0.x,a0.y,a0.z,a0.w},{a1.x,a1.y,a1.z,a1.w},
                          {a2.x,a2.y,a2.z,a2.w},{a3.x,a3.y,a3.z,a3.w}};
        float wv[4][4] = {{w0.x,w0.y,w0.z,w0.w},{w1.x,w1.y,w1.z,w1.w},
                          {w2.x,w2.y,w2.z,w2.w},{w3.x,w3.y,w3.z,w3.w}};
        #pragma unroll
        for (int i = 0; i < 4; i++)
            #pragma unroll
            for (int j = 0; j < 4; j++)
                #pragma unroll
                for (int q = 0; q < 4; q++)
                    acc[i][j] += av[i][q] * wv[q][j];
    }
    float b0 = 0.f, b1 = 0.f, b2 = 0.f, b3 = 0.f;
    if (bias) { b0 = bias[c0]; b1 = bias[c0+1]; b2 = bias[c0+2]; b3 = bias[c0+3]; }
    #pragma unroll
    for (int i = 0; i < 4; i++) {
        int r = row0 + r0 + i;
        if (r >= M) break;
        float4 v;
        v.x = acc[i][0] + b0; v.y = acc[i][1] + b1; v.z = acc[i][2] + b2; v.w = acc[i][3] + b3;
        if (act == 1) { v.x = sspf(v.x); v.y = sspf(v.y); v.z = sspf(v.z); v.w = sspf(v.w); }
        *(float4*)&Y[(size_t)r * 128 + c0] = v;
    }
}

// batched transpose + bf16 quantize of all 26 weight matrices in one launch
struct WArgs { const float* s[26]; unsigned short* d[26]; };
__global__ void wprep_all(WArgs a) {
    __shared__ float tile[32][33];
    int mz = blockIdx.z;
    const float* Wm = a.s[mz];
    unsigned short* Wo = a.d[mz];
    int bx = blockIdx.x * 32, by = blockIdx.y * 32;
    int tx = threadIdx.x & 31, ty = threadIdx.x >> 5;
    for (int r = ty; r < 32; r += 8) tile[r][tx] = Wm[(by + r) * 128 + bx + tx];
    __syncthreads();
    for (int r = ty; r < 32; r += 8) Wo[(bx + r) * 128 + by + tx] = f2bs(tile[tx][r]);
}

// column-split bf16 MFMA GEMM: block = 32 rows, wave w computes cols [32w,32w+32)
__launch_bounds__(256)
__global__ void gemm_cs(const float* __restrict__ A, const unsigned short* __restrict__ Wt,
                        const float* __restrict__ bias,
                        float* __restrict__ Yf, unsigned short* __restrict__ Yb,
                        int M, int act,
                        int aStride, int wStride, int bStride, int yStride) {
    int l = blockIdx.y;
    A += (size_t)l * aStride;
    Wt += (size_t)l * wStride;
    if (bias) bias += (size_t)l * bStride;
    if (Yf) Yf += (size_t)l * yStride;
    if (Yb) Yb += (size_t)l * yStride;
    int wv = threadIdx.x >> 6, lane = threadIdx.x & 63;
    int row0 = blockIdx.x * 32;
    if (row0 >= M) return;
    int lm = lane & 15, lk = (lane >> 4) * 8, orow = (lane >> 4) * 4;
    int r0 = row0 + lm;      r0 = (r0 < M) ? r0 : M - 1;
    int r1 = row0 + 16 + lm; r1 = (r1 < M) ? r1 : M - 1;
    const float* Ap0 = A + (size_t)r0 * 128;
    const float* Ap1 = A + (size_t)r1 * 128;
    short8 af0[4], af1[4];
    #pragma unroll
    for (int kq = 0; kq < 4; kq++) {
        af0[kq] = pack_bf16x8(*(const float4*)(Ap0 + kq * 32 + lk),
                              *(const float4*)(Ap0 + kq * 32 + lk + 4));
        af1[kq] = pack_bf16x8(*(const float4*)(Ap1 + kq * 32 + lk),
                              *(const float4*)(Ap1 + kq * 32 + lk + 4));
    }
    floatx4 acc[2][2];
    #pragma unroll
    for (int i = 0; i < 2; i++)
        #pragma unroll
        for (int j = 0; j < 2; j++) acc[i][j] = (floatx4){0, 0, 0, 0};
    const unsigned short* Wp = Wt + (size_t)(wv * 32) * 128;
    #pragma unroll
    for (int kq = 0; kq < 4; kq++) {
        #pragma unroll
        for (int ct = 0; ct < 2; ct++) {
            short8 bf = *(const short8*)(Wp + (size_t)(ct * 16 + lm) * 128 + kq * 32 + lk);
            acc[0][ct] = __builtin_amdgcn_mfma_f32_16x16x32_bf16(af0[kq], bf, acc[0][ct], 0, 0, 0);
            acc[1][ct] = __builtin_amdgcn_mfma_f32_16x16x32_bf16(af1[kq], bf, acc[1][ct], 0, 0, 0);
        }
    }
    #pragma unroll
    for (int tt = 0; tt < 2; tt++) {
        #pragma unroll
        for (int ct = 0; ct < 2; ct++) {
            int c = wv * 32 + ct * 16 + lm;
            float b = bias ? bias[c] : 0.f;
            #pragma unroll
            for (int r = 0; r < 4; r++) {
                int rr = row0 + tt * 16 + orow + r;
                if (rr >= M) continue;
                float v = acc[tt][ct][r] + b;
                if (act) v = sspf(v);
                if (Yf) Yf[(size_t)rr * 128 + c] = v;
                if (Yb) Yb[(size_t)rr * 128 + c] = f2bs(v);
            }
        }
    }
}

// fused triple GEMM, 16 rows/block (2x TLP vs R5), col-split waves:
//   t1    = ssp(A @ W2t^T + b2)           (LDS round-trip, bf16)
//   h_new = t1 @ W3t^T + b3 [+ resid] -> Yf (fp32)
//   xfb   = bf16(h_new @ W1nt^T)      -> xfb (if W1nt != null)
// Requires M % 16 == 0 (NN = 20000 = 1250*16).
__launch_bounds__(256)
__global__ void gemm3(const float* __restrict__ A,
                      const unsigned short* __restrict__ W2t, const float* __restrict__ b2,
                      const unsigned short* __restrict__ W3t, const float* __restrict__ b3,
                      const float* __restrict__ resid, float* __restrict__ Yf,
                      const unsigned short* __restrict__ W1nt, unsigned short* __restrict__ xfb) {
    __shared__ unsigned short Ls[16 * G2_PAD];
    int wv = threadIdx.x >> 6, lane = threadIdx.x & 63;
    int row0 = blockIdx.x * 16;
    int lm = lane & 15, lk = (lane >> 4) * 8, orow = (lane >> 4) * 4;
    int cw = wv * 32;
    // ---- phase 1: t1 = ssp(A @ W2t^T + b2) -> LDS ----
    {
        const float* Ap = A + (size_t)(row0 + lm) * 128;
        short8 af[4];
        #pragma unroll
        for (int kq = 0; kq < 4; kq++)
            af[kq] = pack_bf16x8(*(const float4*)(Ap + kq * 32 + lk),
                                 *(const float4*)(Ap + kq * 32 + lk + 4));
        floatx4 acc[2];
        acc[0] = (floatx4){0, 0, 0, 0}; acc[1] = (floatx4){0, 0, 0, 0};
        const unsigned short* Wp = W2t + (size_t)cw * 128;
        #pragma unroll
        for (int kq = 0; kq < 4; kq++) {
            #pragma unroll
            for (int ct = 0; ct < 2; ct++) {
                short8 bf = *(const short8*)(Wp + (size_t)(ct * 16 + lm) * 128 + kq * 32 + lk);
                acc[ct] = __builtin_amdgcn_mfma_f32_16x16x32_bf16(af[kq], bf, acc[ct], 0, 0, 0);
            }
        }
        #pragma unroll
        for (int ct = 0; ct < 2; ct++) {
            int c = cw + ct * 16 + lm;
            float b = b2[c];
            #pragma unroll
            for (int r = 0; r < 4; r++)
                Ls[(orow + r) * G2_PAD + c] = f2bs(sspf(acc[ct][r] + b));
        }
    }
    __syncthreads();
    // ---- phase 2: h_new = t1 @ W3t^T + b3 [+resid] -> Yf ----
    float vout[2][4];
    {
        short8 a2[4];
        #pragma unroll
        for (int kq = 0; kq < 4; kq++)
            a2[kq] = *(const short8*)&Ls[lm * G2_PAD + kq * 32 + lk];
        floatx4 acc[2];
        acc[0] = (floatx4){0, 0, 0, 0}; acc[1] = (floatx4){0, 0, 0, 0};
        const unsigned short* Wp = W3t + (size_t)cw * 128;
        #pragma unroll
        for (int kq = 0; kq < 4; kq++) {
            #pragma unroll
            for (int ct = 0; ct < 2; ct++) {
                short8 bf = *(const short8*)(Wp + (size_t)(ct * 16 + lm) * 128 + kq * 32 + lk);
                acc[ct] = __builtin_amdgcn_mfma_f32_16x16x32_bf16(a2[kq], bf, acc[ct], 0, 0, 0);
            }
        }
        #pragma unroll
        for (int ct = 0; ct < 2; ct++) {
            int c = cw + ct * 16 + lm;
            float b = b3[c];
            #pragma unroll
            for (int r = 0; r < 4; r++) {
                int rr = row0 + orow + r;
                float v = acc[ct][r] + b;
                if (resid) v += resid[(size_t)rr * 128 + c];
                Yf[(size_t)rr * 128 + c] = v;
                vout[ct][r] = v;
            }
        }
    }
    if (!W1nt) return;
    __syncthreads();
    #pragma unroll
    for (int ct = 0; ct < 2; ct++) {
        int c = cw + ct * 16 + lm;
        #pragma unroll
        for (int r = 0; r < 4; r++)
            Ls[(orow + r) * G2_PAD + c] = f2bs(vout[ct][r]);
    }
    __syncthreads();
    // ---- phase 3: xfb = bf16(h_new @ W1nt^T) ----
    {
        short8 a3[4];
        #pragma unroll
        for (int kq = 0; kq < 4; kq++)
            a3[kq] = *(const short8*)&Ls[lm * G2_PAD + kq * 32 + lk];
        floatx4 acc[2];
        acc[0] = (floatx4){0, 0, 0, 0}; acc[1] = (floatx4){0, 0, 0, 0};
        const unsigned short* Wp = W1nt + (size_t)cw * 128;
        #pragma unroll
        for (int kq = 0; kq < 4; kq++) {
            #pragma unroll
            for (int ct = 0; ct < 2; ct++) {
                short8 bf = *(const short8*)(Wp + (size_t)(ct * 16 + lm) * 128 + kq * 32 + lk);
                acc[ct] = __builtin_amdgcn_mfma_f32_16x16x32_bf16(a3[kq], bf, acc[ct], 0, 0, 0);
            }
        }
        #pragma unroll
        for (int ct = 0; ct < 2; ct++) {
            int c = cw + ct * 16 + lm;
            #pragma unroll
            for (int r = 0; r < 4; r++)
                xfb[(size_t)(row0 + orow + r) * 128 + c] = f2bs(acc[ct][r]);
        }
    }
}

// fold cutoff C(d) into table; one uint per channel: (dW<<16)|W
__global__ void tquant(const float* __restrict__ T, unsigned int* __restrict__ Tb) {
    int idx = blockIdx.x * blockDim.x + threadIdx.x;
    const int total = LAYERS * (TBL + 1) * 128;
    if (idx >= total) return;
    int c = idx & 127;
    int li = idx >> 7;
    int i = li % (TBL + 1);
    int l = li / (TBL + 1);
    float d0 = (float)i * (DMAXF / (float)TBL);
    float d1 = (float)(i + 1) * (DMAXF / (float)TBL);
    float C0 = 0.5f * (cosf(d0 * 0.31415926535897931f) + 1.0f);
    float C1 = 0.5f * (cosf(d1 * 0.31415926535897931f) + 1.0f);
    const float* row = T + ((size_t)l * (TBL + 2) + i) * 128 + c;
    float w = row[0] * C0;
    float nw = row[128] * C1;
    Tb[idx] = ((unsigned)f2bs(nw - w) << 16) | f2bs(w);
}

__global__ void h_init(const int* __restrict__ z, const float* __restrict__ emb,
                       float* __restrict__ h) {
    int idx = blockIdx.x * blockDim.x + threadIdx.x;
    if (idx >= NN * 32) return;
    int n = idx >> 5, q = idx & 31;
    ((float4*)h)[n * 32 + q] = ((const float4*)emb)[z[n] * 32 + q];
}

// 2 waves per node (64-channel halves); CSR records via scalar loads
__launch_bounds__(256)
__global__ void edge_agg(const int* __restrict__ row_ptr, const int2* __restrict__ csr,
                         const unsigned int* __restrict__ Tb,
                         const unsigned short* __restrict__ xfb,
                         float* __restrict__ agg) {
    int wv = __builtin_amdgcn_readfirstlane(threadIdx.x >> 6);
    int lane = threadIdx.x & 63;
    int n = blockIdx.x * 2 + (wv >> 1);
    if (n >= NN) return;
    int c = (wv & 1) * 64 + lane;
    int e0 = row_ptr[n], e1 = row_ptr[n + 1];
    float ax = 0.f;
    int e = e0;
    for (; e + 8 <= e1; e += 8) {
        int2 ed[8];
        #pragma unroll
        for (int q = 0; q < 8; q++) ed[q] = csr[e + q];
        unsigned int tw[8]; unsigned short xv[8];
        #pragma unroll
        for (int q = 0; q < 8; q++) {
            unsigned int px = (unsigned int)ed[q].x;
            tw[q] = Tb[(px >> 15) * 128 + c];
            xv[q] = xfb[(size_t)(px & 0x7fffu) * 128 + c];
        }
        #pragma unroll
        for (int q = 0; q < 8; q++) {
            float f = __int_as_float(ed[q].y);
            float w = bs2f(tw[q] & 0xffffu), dw = bs2f(tw[q] >> 16);
            float x = bs2f((unsigned int)xv[q]);
            ax = fmaf(x, fmaf(f, dw, w), ax);
        }
    }
    for (; e < e1; e++) {
        int2 ed = csr[e];
        unsigned int px = (unsigned int)ed.x;
        unsigned int tw = Tb[(px >> 15) * 128 + c];
        unsigned short xv = xfb[(size_t)(px & 0x7fffu) * 128 + c];
        float f = __int_as_float(ed.y);
        float w = bs2f(tw & 0xffffu), dw = bs2f(tw >> 16);
        float x = bs2f((unsigned int)xv);
        ax = fmaf(x, fmaf(f, dw, w), ax);
    }
    agg[(size_t)n * 128 + c] = ax;
}

// parallel mean readout: run-accumulate chunks with atomic flush, then divide
#define RCHUNK 32
__global__ void raccum(const float* __restrict__ hout, const int* __restrict__ batch,
                       float* __restrict__ out) {
    int b = blockIdx.x, c = threadIdx.x;
    int n0 = b * RCHUNK;
    if (n0 >= NN) return;
    int n1 = n0 + RCHUNK; if (n1 > NN) n1 = NN;
    int g = batch[n0];
    float s = 0.f;
    for (int n = n0; n < n1; n++) {
        int bg = batch[n];
        if (bg != g) { atomicAdd(&out[g * 128 + c], s); s = 0.f; g = bg; }
        s += hout[(size_t)n * 128 + c];
    }
    atomicAdd(&out[g * 128 + c], s);
}

__global__ void rdiv(const int* __restrict__ batch, float* __restrict__ out) {
    int g = blockIdx.x;
    int c = threadIdx.x;
    __shared__ int sh[2];
    if (c < 2) {
        int target = g + c;
        int lo = 0, hi = NN;
        while (lo < hi) {
            int mid = (lo + hi) >> 1;
            if (batch[mid] < target) lo = mid + 1; else hi = mid;
        }
        sh[c] = lo;
    }
    __syncthreads();
    int cnt = sh[1] - sh[0];
    out[g * 128 + c] /= (float)(cnt > 0 ? cnt : 1);
}

extern "C" void kernel_launch(void* const* d_in, const int* in_sizes, int n_in,
                              void* d_out, int out_size, void* d_ws, size_t ws_size,
                              hipStream_t stream) {
    const int*   z       = (const int*)d_in[0];
    const float* pos     = (const float*)d_in[1];
    const int*   eidx    = (const int*)d_in[2];
    const int*   src     = eidx;
    const int*   dst     = eidx + NE;
    const int*   batch   = (const int*)d_in[3];
    const float* emb     = (const float*)d_in[4];
    const float* mlp_w1  = (const float*)d_in[5];
    const float* mlp_b1  = (const float*)d_in[6];
    const float* mlp_w2  = (const float*)d_in[7];
    const float* mlp_b2  = (const float*)d_in[8];
    const float* conv_w1 = (const float*)d_in[9];
    const float* conv_w2 = (const float*)d_in[10];
    const float* conv_b2 = (const float*)d_in[11];
    const float* lin_w   = (const float*)d_in[12];
    const float* lin_b   = (const float*)d_in[13];
    const float* out1_w  = (const float*)d_in[14];
    const float* out1_b  = (const float*)d_in[15];
    const float* out2_w  = (const float*)d_in[16];
    const float* out2_b  = (const float*)d_in[17];
    float* out = (float*)d_out;

    char* wp = (char*)d_ws;
    auto alloc = [&](size_t bytes) {
        char* p = wp;
        wp += (bytes + 255) & ~(size_t)255;
        return p;
    };
    const int Mt = TBL + 2;
    int*    deg     = (int*)alloc(NN * 4);
    int*    row_ptr = (int*)alloc((NN + 1) * 4);
    int*    cursor  = (int*)alloc(NN * 4);
    int2*   csr     = (int2*)alloc((size_t)NE * 8);
    float*  A_tab   = (float*)alloc((size_t)Mt * GDIM * 4);
    float*  T1all   = (float*)alloc((size_t)LAYERS * Mt * 128 * 4);
    float*  T       = (float*)alloc((size_t)LAYERS * Mt * 128 * 4);
    unsigned int* Tb = (unsigned int*)alloc((size_t)LAYERS * (TBL + 1) * 128 * 4);
    float*  h       = (float*)alloc((size_t)NN * 128 * 4);
    float*  agg     = (float*)alloc((size_t)NN * 128 * 4);
    unsigned short* xfb = (unsigned short*)alloc((size_t)NN * 128 * 2);
    unsigned short* wbf = (unsigned short*)alloc((size_t)26 * 16384 * 2);
    unsigned short* mlp_w2t  = wbf;
    unsigned short* conv_w1t = wbf + (size_t)6 * 16384;
    unsigned short* conv_w2t = wbf + (size_t)12 * 16384;
    unsigned short* lin_wt   = wbf + (size_t)18 * 16384;
    unsigned short* out1_wt  = wbf + (size_t)24 * 16384;
    unsigned short* out2_wt  = wbf + (size_t)25 * 16384;

    // init (deg=0, out=0, gaussian attr table)
    const int initN = NN + NGRAPH * 128 + Mt * GDIM;
    init_misc<<<(initN + 255) / 256, 256, 0, stream>>>(deg, out, A_tab);

    // graph structure
    deg_hist<<<(NE + 255) / 256, 256, 0, stream>>>(dst, deg);
    scan_deg<<<1, 1024, 0, stream>>>(deg, row_ptr, cursor);
    csr_fill<<<(NE + 255) / 256, 256, 0, stream>>>(pos, src, dst, cursor, csr);

    // all weight transposes in one launch
    WArgs wa;
    for (int l = 0; l < 6; l++) {
        wa.s[l]      = mlp_w2  + (size_t)l * 16384;  wa.d[l]      = mlp_w2t  + (size_t)l * 16384;
        wa.s[6 + l]  = conv_w1 + (size_t)l * 16384;  wa.d[6 + l]  = conv_w1t + (size_t)l * 16384;
        wa.s[12 + l] = conv_w2 + (size_t)l * 16384;  wa.d[12 + l] = conv_w2t + (size_t)l * 16384;
        wa.s[18 + l] = lin_w   + (size_t)l * 16384;  wa.d[18 + l] = lin_wt   + (size_t)l * 16384;
    }
    wa.s[24] = out1_w; wa.d[24] = out1_wt;
    wa.s[25] = out2_w; wa.d[25] = out2_wt;
    wprep_all<<<dim3(4, 4, 26), 256, 0, stream>>>(wa);

    // filter tables
    const int gt32 = (Mt + 31) / 32;
    gemm_t<GDIM><<<dim3(gt32, LAYERS), 256, 0, stream>>>(
        A_tab, mlp_w1, mlp_b1, T1all, Mt, 1, 0, GDIM * 128, 128, Mt * 128);
    gemm_cs<<<dim3(gt32, LAYERS), 256, 0, stream>>>(
        T1all, mlp_w2t, mlp_b2, T, nullptr, Mt, 0,
        Mt * 128, 16384, 128, Mt * 128);
    tquant<<<(LAYERS * (TBL + 1) * 128 + 255) / 256, 256, 0, stream>>>(T, Tb);

    // node embedding + layer-0 conv filter input
    h_init<<<(NN * 32 + 255) / 256, 256, 0, stream>>>(z, emb, h);
    gemm_cs<<<NN / 32, 256, 0, stream>>>(h, conv_w1t, nullptr, nullptr, xfb, NN, 0, 0, 0, 0, 0);

    const int gn = NN / 16;   // 1250, exact
    for (int l = 0; l < LAYERS; l++) {
        edge_agg<<<NN / 2, 256, 0, stream>>>(row_ptr, csr,
                                             Tb + (size_t)l * (TBL + 1) * 128,
                                             xfb, agg);
        // h = h + ssp(agg @ conv_w2[l] + b2) @ lin_w[l] + lin_b[l]; xfb = h @ conv_w1[l+1]
        const unsigned short* w1n = (l + 1 < LAYERS) ? conv_w1t + (size_t)(l + 1) * 16384 : nullptr;
        gemm3<<<gn, 256, 0, stream>>>(agg, conv_w2t + (size_t)l * 16384, conv_b2 + l * 128,
                                      lin_wt + (size_t)l * 16384, lin_b + l * 128,
                                      h, h, w1n, xfb);
    }

    // output head (fused): hout = ssp(h @ out1 + b1) @ out2 + b2
    gemm3<<<gn, 256, 0, stream>>>(h, out1_wt, out1_b, out2_wt, out2_b,
                                  nullptr, agg, nullptr, nullptr);

    // per-graph mean
    raccum<<<(NN + RCHUNK - 1) / RCHUNK, 128, 0, stream>>>(agg, batch, out);
    rdiv<<<NGRAPH, 128, 0, stream>>>(batch, out);
}

// Round 7
// 553.369 us; speedup vs baseline: 2.9593x; 1.1222x over previous
//
#include <hip/hip_runtime.h>
#include <math.h>

#define NN 20000
#define NE 640000
#define GDIM 50
#define LAYERS 6
#define NGRAPH 64
#define TBL 2048
#define DMAXF 12.8f
#define G2_PAD 136   // LDS row stride in shorts (128 + 8 pad)

typedef __attribute__((ext_vector_type(8))) short short8;
typedef __attribute__((ext_vector_type(4))) float floatx4;

__device__ __forceinline__ float sspf(float x) {
    float sp = (x > 30.0f) ? x : log1pf(expf(x));
    return sp - 0.69314718055994530942f;
}

__device__ __forceinline__ unsigned short f2bs(float f) {
    union { float f; unsigned int i; } u; u.f = f;
    unsigned int r = u.i + 0x7fffu + ((u.i >> 16) & 1u);
    return (unsigned short)(r >> 16);
}

__device__ __forceinline__ float bs2f(unsigned int bits16) {
    union { unsigned int i; float f; } u; u.i = bits16 << 16;
    return u.f;
}

__device__ __forceinline__ short8 pack_bf16x8(float4 a, float4 b) {
    short8 o;
    o[0] = (short)f2bs(a.x); o[1] = (short)f2bs(a.y);
    o[2] = (short)f2bs(a.z); o[3] = (short)f2bs(a.w);
    o[4] = (short)f2bs(b.x); o[5] = (short)f2bs(b.y);
    o[6] = (short)f2bs(b.z); o[7] = (short)f2bs(b.w);
    return o;
}

// ---- merged prep: 26 weight transposes + deg=0 + out=0 + gaussian table + h_init ----
struct WArgs { const float* s[26]; unsigned short* d[26]; };
#define PREP_WBLK 416            // 26 matrices x 16 tiles
__global__ void prep_a(WArgs a, int* __restrict__ deg, float* __restrict__ out,
                       float* __restrict__ A_tab, const int* __restrict__ z,
                       const float* __restrict__ emb, float* __restrict__ h) {
    __shared__ float tile[32][33];
    int b = blockIdx.x;
    if (b < PREP_WBLK) {
        int mz = b >> 4, sub = b & 15;
        int bx = (sub & 3) * 32, by = (sub >> 2) * 32;
        const float* Wm = a.s[mz];
        unsigned short* Wo = a.d[mz];
        int tx = threadIdx.x & 31, ty = threadIdx.x >> 5;
        for (int r = ty; r < 32; r += 8) tile[r][tx] = Wm[(by + r) * 128 + bx + tx];
        __syncthreads();
        for (int r = ty; r < 32; r += 8) Wo[(bx + r) * 128 + by + tx] = f2bs(tile[tx][r]);
        return;
    }
    int idx = (b - PREP_WBLK) * 256 + threadIdx.x;
    if (idx < NN) { deg[idx] = 0; return; }
    idx -= NN;
    if (idx < NGRAPH * 128) { out[idx] = 0.f; return; }
    idx -= NGRAPH * 128;
    if (idx < (TBL + 2) * GDIM) {
        int i = idx / GDIM, g = idx % GDIM;
        float v = 0.0f;
        if (i <= TBL) {
            float d = (float)i * (DMAXF / (float)TBL);
            float step = 10.0f / 49.0f;
            float off = (float)g * step;
            float coeff = -0.5f / (step * step);
            float dd = d - off;
            v = expf(coeff * dd * dd);
        }
        A_tab[idx] = v;
        return;
    }
    idx -= (TBL + 2) * GDIM;
    if (idx < NN * 32) {
        int n = idx >> 5, q = idx & 31;
        ((float4*)h)[n * 32 + q] = ((const float4*)emb)[(size_t)z[n] * 32 + q];
    }
}

__global__ void deg_hist(const int* __restrict__ dst, int* __restrict__ deg) {
    int j = blockIdx.x * blockDim.x + threadIdx.x;
    if (j >= NE) return;
    atomicAdd(&deg[dst[j]], 1);
}

// hierarchical scan: local 256-scan + blocksums
__global__ void scan_a(const int* __restrict__ deg, int* __restrict__ row_ptr,
                       int* __restrict__ bsum) {
    __shared__ int sh[256];
    int b = blockIdx.x, t = threadIdx.x;
    int i = b * 256 + t;
    int v = (i < NN) ? deg[i] : 0;
    int x = v;
    sh[t] = x;
    __syncthreads();
    for (int off = 1; off < 256; off <<= 1) {
        int u = (t >= off) ? sh[t - off] : 0;
        __syncthreads();
        x += u;
        sh[t] = x;
        __syncthreads();
    }
    if (i <= NN) row_ptr[i] = x - v;   // local exclusive
    if (t == 255) bsum[b] = x;
}

// add block-prefix offsets; init cursor
__global__ void scan_b(const int* __restrict__ bsum, int* __restrict__ row_ptr,
                       int* __restrict__ cursor) {
    __shared__ int spref;
    int b = blockIdx.x, t = threadIdx.x;
    if (t < 64) {
        int s = 0;
        if (t < b) s += bsum[t];
        if (t + 64 < b) s += bsum[t + 64];
        for (int off = 32; off; off >>= 1) s += __shfl_down(s, off);
        if (t == 0) spref = s;
    }
    __syncthreads();
    int prefix = spref;
    int i = b * 256 + t;
    if (i < NN) {
        int v = row_ptr[i] + prefix;
        row_ptr[i] = v;
        cursor[i] = v;
    }
    if (b == 0 && t == 0) row_ptr[NN] = NE;
}

// CSR entry: int2{ (i0<<15)|src , bits(f) }   (cutoff C folded into table)
__global__ void csr_fill(const float* __restrict__ pos, const int* __restrict__ src,
                         const int* __restrict__ dst, int* __restrict__ cursor,
                         int2* __restrict__ csr) {
    int j = blockIdx.x * blockDim.x + threadIdx.x;
    if (j >= NE) return;
    int s = src[j], tno = dst[j];
    float dx = pos[3*s+0] - pos[3*tno+0];
    float dy = pos[3*s+1] - pos[3*tno+1];
    float dz = pos[3*s+2] - pos[3*tno+2];
    float d = sqrtf(dx*dx + dy*dy + dz*dz);
    float u = d * ((float)TBL / DMAXF);
    u = fminf(u, (float)(TBL + 1));
    int i0 = (int)u; if (i0 > TBL) i0 = TBL;
    float f = u - (float)i0;
    int p = atomicAdd(&cursor[tno], 1);
    csr[p] = make_int2((i0 << 15) | s, __float_as_int(f));
}

// fp32 tiled GEMM for the K=50 table stage only, batched over gridDim.y
template <int K>
__launch_bounds__(256, 2)
__global__ void gemm_t(const float* __restrict__ A, const float* __restrict__ W,
                       const float* __restrict__ bias, float* __restrict__ Y, int M,
                       int act, int aStride, int wStride, int bStride, int yStride) {
    constexpr int KP = (K + 3) & ~3;
    __shared__ __align__(16) float Ws[KP * 128];
    __shared__ __align__(16) float As[32 * KP];
    int l = blockIdx.y;
    A += (size_t)l * aStride;
    W += (size_t)l * wStride;
    if (bias) bias += (size_t)l * bStride;
    Y += (size_t)l * yStride;
    int t = threadIdx.x;
    int row0 = blockIdx.x * 32;
    for (int i = t; i < KP * 128; i += 256) Ws[i] = (i < K * 128) ? W[i] : 0.0f;
    for (int i = t; i < 32 * KP; i += 256) {
        int r = i / KP, k = i % KP;
        float v = 0.f;
        if (k < K && row0 + r < M) v = A[(size_t)(row0 + r) * K + k];
        As[r * KP + k] = v;
    }
    __syncthreads();
    int tx = t & 31, ty = t >> 5;
    int c0 = tx * 4, r0 = ty * 4;
    float acc[4][4] = {{0.f}};
    #pragma unroll 4
    for (int k = 0; k < KP; k += 4) {
        float4 a0 = *(const float4*)&As[(r0 + 0) * KP + k];
        float4 a1 = *(const float4*)&As[(r0 + 1) * KP + k];
        float4 a2 = *(const float4*)&As[(r0 + 2) * KP + k];
        float4 a3 = *(const float4*)&As[(r0 + 3) * KP + k];
        float4 w0 = *(const float4*)&Ws[(k + 0) * 128 + c0];
        float4 w1 = *(const float4*)&Ws[(k + 1) * 128 + c0];
        float4 w2 = *(const float4*)&Ws[(k + 2) * 128 + c0];
        float4 w3 = *(const float4*)&Ws[(k + 3) * 128 + c0];
        float av[4][4] = {{a0.x,a0.y,a0.z,a0.w},{a1.x,a1.y,a1.z,a1.w},
                          {a2.x,a2.y,a2.z,a2.w},{a3.x,a3.y,a3.z,a3.w}};
        float wv[4][4] = {{w0.x,w0.y,w0.z,w0.w},{w1.x,w1.y,w1.z,w1.w},
                          {w2.x,w2.y,w2.z,w2.w},{w3.x,w3.y,w3.z,w3.w}};
        #pragma unroll
        for (int i = 0; i < 4; i++)
            #pragma unroll
            for (int j = 0; j < 4; j++)
                #pragma unroll
                for (int q = 0; q < 4; q++)
                    acc[i][j] += av[i][q] * wv[q][j];
    }
    float b0 = 0.f, b1 = 0.f, b2 = 0.f, b3 = 0.f;
    if (bias) { b0 = bias[c0]; b1 = bias[c0+1]; b2 = bias[c0+2]; b3 = bias[c0+3]; }
    #pragma unroll
    for (int i = 0; i < 4; i++) {
        int r = row0 + r0 + i;
        if (r >= M) break;
        float4 v;
        v.x = acc[i][0] + b0; v.y = acc[i][1] + b1; v.z = acc[i][2] + b2; v.w = acc[i][3] + b3;
        if (act == 1) { v.x = sspf(v.x); v.y = sspf(v.y); v.z = sspf(v.z); v.w = sspf(v.w); }
        *(float4*)&Y[(size_t)r * 128 + c0] = v;
    }
}

// merged col-split MFMA GEMM: y<6 -> table layer y (A1/W1/bias1 -> Y1 fp32);
// y==6 -> xfb job (A2 @ W2 -> Yb2 bf16)
__launch_bounds__(256)
__global__ void gemm_cs2(const float* __restrict__ A1, const unsigned short* __restrict__ W1t,
                         const float* __restrict__ bias1, float* __restrict__ Y1, int M1,
                         const float* __restrict__ A2, const unsigned short* __restrict__ W2t,
                         unsigned short* __restrict__ Yb2, int M2) {
    int y = blockIdx.y;
    const float* A; const unsigned short* Wt; const float* bias;
    float* Yf; unsigned short* Yb; int M;
    if (y < LAYERS) {
        M = M1;
        A = A1 + (size_t)y * M1 * 128;
        Wt = W1t + (size_t)y * 16384;
        bias = bias1 + (size_t)y * 128;
        Yf = Y1 + (size_t)y * M1 * 128;
        Yb = nullptr;
    } else {
        M = M2; A = A2; Wt = W2t; bias = nullptr; Yf = nullptr; Yb = Yb2;
    }
    int wv = threadIdx.x >> 6, lane = threadIdx.x & 63;
    int row0 = blockIdx.x * 32;
    if (row0 >= M) return;
    int lm = lane & 15, lk = (lane >> 4) * 8, orow = (lane >> 4) * 4;
    int r0 = row0 + lm;      r0 = (r0 < M) ? r0 : M - 1;
    int r1 = row0 + 16 + lm; r1 = (r1 < M) ? r1 : M - 1;
    const float* Ap0 = A + (size_t)r0 * 128;
    const float* Ap1 = A + (size_t)r1 * 128;
    short8 af0[4], af1[4];
    #pragma unroll
    for (int kq = 0; kq < 4; kq++) {
        af0[kq] = pack_bf16x8(*(const float4*)(Ap0 + kq * 32 + lk),
                              *(const float4*)(Ap0 + kq * 32 + lk + 4));
        af1[kq] = pack_bf16x8(*(const float4*)(Ap1 + kq * 32 + lk),
                              *(const float4*)(Ap1 + kq * 32 + lk + 4));
    }
    floatx4 acc[2][2];
    #pragma unroll
    for (int i = 0; i < 2; i++)
        #pragma unroll
        for (int j = 0; j < 2; j++) acc[i][j] = (floatx4){0, 0, 0, 0};
    const unsigned short* Wp = Wt + (size_t)(wv * 32) * 128;
    #pragma unroll
    for (int kq = 0; kq < 4; kq++) {
        #pragma unroll
        for (int ct = 0; ct < 2; ct++) {
            short8 bf = *(const short8*)(Wp + (size_t)(ct * 16 + lm) * 128 + kq * 32 + lk);
            acc[0][ct] = __builtin_amdgcn_mfma_f32_16x16x32_bf16(af0[kq], bf, acc[0][ct], 0, 0, 0);
            acc[1][ct] = __builtin_amdgcn_mfma_f32_16x16x32_bf16(af1[kq], bf, acc[1][ct], 0, 0, 0);
        }
    }
    #pragma unroll
    for (int tt = 0; tt < 2; tt++) {
        #pragma unroll
        for (int ct = 0; ct < 2; ct++) {
            int c = wv * 32 + ct * 16 + lm;
            float b = bias ? bias[c] : 0.f;
            #pragma unroll
            for (int r = 0; r < 4; r++) {
                int rr = row0 + tt * 16 + orow + r;
                if (rr >= M) continue;
                float v = acc[tt][ct][r] + b;
                if (Yf) Yf[(size_t)rr * 128 + c] = v;
                if (Yb) Yb[(size_t)rr * 128 + c] = f2bs(v);
            }
        }
    }
}

// fused triple GEMM, 16 rows/block, col-split waves; resid prefetched at entry
__launch_bounds__(256)
__global__ void gemm3(const float* __restrict__ A,
                      const unsigned short* __restrict__ W2t, const float* __restrict__ b2,
                      const unsigned short* __restrict__ W3t, const float* __restrict__ b3,
                      const float* __restrict__ resid, float* __restrict__ Yf,
                      const unsigned short* __restrict__ W1nt, unsigned short* __restrict__ xfb) {
    __shared__ unsigned short Ls[16 * G2_PAD];
    int wv = threadIdx.x >> 6, lane = threadIdx.x & 63;
    int row0 = blockIdx.x * 16;
    int lm = lane & 15, lk = (lane >> 4) * 8, orow = (lane >> 4) * 4;
    int cw = wv * 32;
    // prefetch residual rows early (consumed at phase-2 epilogue)
    float rpre[2][4];
    if (resid) {
        #pragma unroll
        for (int ct = 0; ct < 2; ct++)
            #pragma unroll
            for (int r = 0; r < 4; r++)
                rpre[ct][r] = resid[(size_t)(row0 + orow + r) * 128 + cw + ct * 16 + lm];
    }
    // ---- phase 1: t1 = ssp(A @ W2t^T + b2) -> LDS ----
    {
        const float* Ap = A + (size_t)(row0 + lm) * 128;
        short8 af[4];
        #pragma unroll
        for (int kq = 0; kq < 4; kq++)
            af[kq] = pack_bf16x8(*(const float4*)(Ap + kq * 32 + lk),
                                 *(const float4*)(Ap + kq * 32 + lk + 4));
        floatx4 acc[2];
        acc[0] = (floatx4){0, 0, 0, 0}; acc[1] = (floatx4){0, 0, 0, 0};
        const unsigned short* Wp = W2t + (size_t)cw * 128;
        #pragma unroll
        for (int kq = 0; kq < 4; kq++) {
            #pragma unroll
            for (int ct = 0; ct < 2; ct++) {
                short8 bf = *(const short8*)(Wp + (size_t)(ct * 16 + lm) * 128 + kq * 32 + lk);
                acc[ct] = __builtin_amdgcn_mfma_f32_16x16x32_bf16(af[kq], bf, acc[ct], 0, 0, 0);
            }
        }
        #pragma unroll
        for (int ct = 0; ct < 2; ct++) {
            int c = cw + ct * 16 + lm;
            float b = b2[c];
            #pragma unroll
            for (int r = 0; r < 4; r++)
                Ls[(orow + r) * G2_PAD + c] = f2bs(sspf(acc[ct][r] + b));
        }
    }
    __syncthreads();
    // ---- phase 2: h_new = t1 @ W3t^T + b3 [+resid] -> Yf ----
    float vout[2][4];
    {
        short8 a2[4];
        #pragma unroll
        for (int kq = 0; kq < 4; kq++)
            a2[kq] = *(const short8*)&Ls[lm * G2_PAD + kq * 32 + lk];
        floatx4 acc[2];
        acc[0] = (floatx4){0, 0, 0, 0}; acc[1] = (floatx4){0, 0, 0, 0};
        const unsigned short* Wp = W3t + (size_t)cw * 128;
        #pragma unroll
        for (int kq = 0; kq < 4; kq++) {
            #pragma unroll
            for (int ct = 0; ct < 2; ct++) {
                short8 bf = *(const short8*)(Wp + (size_t)(ct * 16 + lm) * 128 + kq * 32 + lk);
                acc[ct] = __builtin_amdgcn_mfma_f32_16x16x32_bf16(a2[kq], bf, acc[ct], 0, 0, 0);
            }
        }
        #pragma unroll
        for (int ct = 0; ct < 2; ct++) {
            int c = cw + ct * 16 + lm;
            float b = b3[c];
            #pragma unroll
            for (int r = 0; r < 4; r++) {
                int rr = row0 + orow + r;
                float v = acc[ct][r] + b;
                if (resid) v += rpre[ct][r];
                Yf[(size_t)rr * 128 + c] = v;
                vout[ct][r] = v;
            }
        }
    }
    if (!W1nt) return;
    __syncthreads();
    #pragma unroll
    for (int ct = 0; ct < 2; ct++) {
        int c = cw + ct * 16 + lm;
        #pragma unroll
        for (int r = 0; r < 4; r++)
            Ls[(orow + r) * G2_PAD + c] = f2bs(vout[ct][r]);
    }
    __syncthreads();
    // ---- phase 3: xfb = bf16(h_new @ W1nt^T) ----
    {
        short8 a3[4];
        #pragma unroll
        for (int kq = 0; kq < 4; kq++)
            a3[kq] = *(const short8*)&Ls[lm * G2_PAD + kq * 32 + lk];
        floatx4 acc[2];
        acc[0] = (floatx4){0, 0, 0, 0}; acc[1] = (floatx4){0, 0, 0, 0};
        const unsigned short* Wp = W1nt + (size_t)cw * 128;
        #pragma unroll
        for (int kq = 0; kq < 4; kq++) {
            #pragma unroll
            for (int ct = 0; ct < 2; ct++) {
                short8 bf = *(const short8*)(Wp + (size_t)(ct * 16 + lm) * 128 + kq * 32 + lk);
                acc[ct] = __builtin_amdgcn_mfma_f32_16x16x32_bf16(a3[kq], bf, acc[ct], 0, 0, 0);
            }
        }
        #pragma unroll
        for (int ct = 0; ct < 2; ct++) {
            int c = cw + ct * 16 + lm;
            #pragma unroll
            for (int r = 0; r < 4; r++)
                xfb[(size_t)(row0 + orow + r) * 128 + c] = f2bs(acc[ct][r]);
        }
    }
}

// fold cutoff C(d) into table; one uint per channel: (dW<<16)|W
__global__ void tquant(const float* __restrict__ T, unsigned int* __restrict__ Tb) {
    int idx = blockIdx.x * blockDim.x + threadIdx.x;
    const int total = LAYERS * (TBL + 1) * 128;
    if (idx >= total) return;
    int c = idx & 127;
    int li = idx >> 7;
    int i = li % (TBL + 1);
    int l = li / (TBL + 1);
    float d0 = (float)i * (DMAXF / (float)TBL);
    float d1 = (float)(i + 1) * (DMAXF / (float)TBL);
    float C0 = 0.5f * (cosf(d0 * 0.31415926535897931f) + 1.0f);
    float C1 = 0.5f * (cosf(d1 * 0.31415926535897931f) + 1.0f);
    const float* row = T + ((size_t)l * (TBL + 2) + i) * 128 + c;
    float w = row[0] * C0;
    float nw = row[128] * C1;
    Tb[idx] = ((unsigned)f2bs(nw - w) << 16) | f2bs(w);
}

// 2 waves per node (64-channel halves); CSR records uniform -> scalar path; 16x unroll
__launch_bounds__(256)
__global__ void edge_agg(const int* __restrict__ row_ptr, const int2* __restrict__ csr,
                         const unsigned int* __restrict__ Tb,
                         const unsigned short* __restrict__ xfb,
                         float* __restrict__ agg) {
    int wv = __builtin_amdgcn_readfirstlane(threadIdx.x >> 6);
    int lane = threadIdx.x & 63;
    int n = blockIdx.x * 2 + (wv >> 1);
    int c = (wv & 1) * 64 + lane;
    int e0 = row_ptr[n], e1 = row_ptr[n + 1];
    float ax = 0.f;
    int e = e0;
    for (; e + 16 <= e1; e += 16) {
        unsigned int px[16]; float ff[16];
        #pragma unroll
        for (int q = 0; q < 16; q++) {
            int2 ed = csr[e + q];
            px[q] = (unsigned int)__builtin_amdgcn_readfirstlane(ed.x);
            ff[q] = __int_as_float(__builtin_amdgcn_readfirstlane(ed.y));
        }
        unsigned int tw[16]; unsigned short xv[16];
        #pragma unroll
        for (int q = 0; q < 16; q++) {
            tw[q] = Tb[(px[q] >> 15) * 128 + c];
            xv[q] = xfb[(size_t)(px[q] & 0x7fffu) * 128 + c];
        }
        #pragma unroll
        for (int q = 0; q < 16; q++) {
            float w = bs2f(tw[q] & 0xffffu), dw = bs2f(tw[q] >> 16);
            float x = bs2f((unsigned int)xv[q]);
            ax = fmaf(x, fmaf(ff[q], dw, w), ax);
        }
    }
    for (; e + 4 <= e1; e += 4) {
        unsigned int px[4]; float ff[4];
        #pragma unroll
        for (int q = 0; q < 4; q++) {
            int2 ed = csr[e + q];
            px[q] = (unsigned int)__builtin_amdgcn_readfirstlane(ed.x);
            ff[q] = __int_as_float(__builtin_amdgcn_readfirstlane(ed.y));
        }
        unsigned int tw[4]; unsigned short xv[4];
        #pragma unroll
        for (int q = 0; q < 4; q++) {
            tw[q] = Tb[(px[q] >> 15) * 128 + c];
            xv[q] = xfb[(size_t)(px[q] & 0x7fffu) * 128 + c];
        }
        #pragma unroll
        for (int q = 0; q < 4; q++) {
            float w = bs2f(tw[q] & 0xffffu), dw = bs2f(tw[q] >> 16);
            float x = bs2f((unsigned int)xv[q]);
            ax = fmaf(x, fmaf(ff[q], dw, w), ax);
        }
    }
    for (; e < e1; e++) {
        int2 ed = csr[e];
        unsigned int px = (unsigned int)__builtin_amdgcn_readfirstlane(ed.x);
        float f = __int_as_float(__builtin_amdgcn_readfirstlane(ed.y));
        unsigned int tw = Tb[(px >> 15) * 128 + c];
        unsigned short xv = xfb[(size_t)(px & 0x7fffu) * 128 + c];
        float w = bs2f(tw & 0xffffu), dw = bs2f(tw >> 16);
        float x = bs2f((unsigned int)xv);
        ax = fmaf(x, fmaf(f, dw, w), ax);
    }
    agg[(size_t)n * 128 + c] = ax;
}

// parallel mean readout: run-accumulate chunks with atomic flush, then divide
#define RCHUNK 32
__global__ void raccum(const float* __restrict__ hout, const int* __restrict__ batch,
                       float* __restrict__ out) {
    int b = blockIdx.x, c = threadIdx.x;
    int n0 = b * RCHUNK;
    if (n0 >= NN) return;
    int n1 = n0 + RCHUNK; if (n1 > NN) n1 = NN;
    int g = batch[n0];
    float s = 0.f;
    for (int n = n0; n < n1; n++) {
        int bg = batch[n];
        if (bg != g) { atomicAdd(&out[g * 128 + c], s); s = 0.f; g = bg; }
        s += hout[(size_t)n * 128 + c];
    }
    atomicAdd(&out[g * 128 + c], s);
}

__global__ void rdiv(const int* __restrict__ batch, float* __restrict__ out) {
    int g = blockIdx.x;
    int c = threadIdx.x;
    __shared__ int sh[2];
    if (c < 2) {
        int target = g + c;
        int lo = 0, hi = NN;
        while (lo < hi) {
            int mid = (lo + hi) >> 1;
            if (batch[mid] < target) lo = mid + 1; else hi = mid;
        }
        sh[c] = lo;
    }
    __syncthreads();
    int cnt = sh[1] - sh[0];
    out[g * 128 + c] /= (float)(cnt > 0 ? cnt : 1);
}

extern "C" void kernel_launch(void* const* d_in, const int* in_sizes, int n_in,
                              void* d_out, int out_size, void* d_ws, size_t ws_size,
                              hipStream_t stream) {
    const int*   z       = (const int*)d_in[0];
    const float* pos     = (const float*)d_in[1];
    const int*   eidx    = (const int*)d_in[2];
    const int*   src     = eidx;
    const int*   dst     = eidx + NE;
    const int*   batch   = (const int*)d_in[3];
    const float* emb     = (const float*)d_in[4];
    const float* mlp_w1  = (const float*)d_in[5];
    const float* mlp_b1  = (const float*)d_in[6];
    const float* mlp_w2  = (const float*)d_in[7];
    const float* mlp_b2  = (const float*)d_in[8];
    const float* conv_w1 = (const float*)d_in[9];
    const float* conv_w2 = (const float*)d_in[10];
    const float* conv_b2 = (const float*)d_in[11];
    const float* lin_w   = (const float*)d_in[12];
    const float* lin_b   = (const float*)d_in[13];
    const float* out1_w  = (const float*)d_in[14];
    const float* out1_b  = (const float*)d_in[15];
    const float* out2_w  = (const float*)d_in[16];
    const float* out2_b  = (const float*)d_in[17];
    float* out = (float*)d_out;

    char* wp = (char*)d_ws;
    auto alloc = [&](size_t bytes) {
        char* p = wp;
        wp += (bytes + 255) & ~(size_t)255;
        return p;
    };
    const int Mt = TBL + 2;
    int*    deg     = (int*)alloc(NN * 4);
    int*    row_ptr = (int*)alloc((NN + 1) * 4);
    int*    cursor  = (int*)alloc(NN * 4);
    int*    bsum    = (int*)alloc(128 * 4);
    int2*   csr     = (int2*)alloc((size_t)NE * 8);
    float*  A_tab   = (float*)alloc((size_t)Mt * GDIM * 4);
    float*  T1all   = (float*)alloc((size_t)LAYERS * Mt * 128 * 4);
    float*  T       = (float*)alloc((size_t)LAYERS * Mt * 128 * 4);
    unsigned int* Tb = (unsigned int*)alloc((size_t)LAYERS * (TBL + 1) * 128 * 4);
    float*  h       = (float*)alloc((size_t)NN * 128 * 4);
    float*  agg     = (float*)alloc((size_t)NN * 128 * 4);
    unsigned short* xfb = (unsigned short*)alloc((size_t)NN * 128 * 2);
    unsigned short* wbf = (unsigned short*)alloc((size_t)26 * 16384 * 2);
    unsigned short* mlp_w2t  = wbf;
    unsigned short* conv_w1t = wbf + (size_t)6 * 16384;
    unsigned short* conv_w2t = wbf + (size_t)12 * 16384;
    unsigned short* lin_wt   = wbf + (size_t)18 * 16384;
    unsigned short* out1_wt  = wbf + (size_t)24 * 16384;
    unsigned short* out2_wt  = wbf + (size_t)25 * 16384;

    // merged prep: weight transposes + zero-init + gaussian table + h_init
    WArgs wa;
    for (int l = 0; l < 6; l++) {
        wa.s[l]      = mlp_w2  + (size_t)l * 16384;  wa.d[l]      = mlp_w2t  + (size_t)l * 16384;
        wa.s[6 + l]  = conv_w1 + (size_t)l * 16384;  wa.d[6 + l]  = conv_w1t + (size_t)l * 16384;
        wa.s[12 + l] = conv_w2 + (size_t)l * 16384;  wa.d[12 + l] = conv_w2t + (size_t)l * 16384;
        wa.s[18 + l] = lin_w   + (size_t)l * 16384;  wa.d[18 + l] = lin_wt   + (size_t)l * 16384;
    }
    wa.s[24] = out1_w; wa.d[24] = out1_wt;
    wa.s[25] = out2_w; wa.d[25] = out2_wt;
    const int initN = NN + NGRAPH * 128 + Mt * GDIM + NN * 32;
    prep_a<<<PREP_WBLK + (initN + 255) / 256, 256, 0, stream>>>(wa, deg, out, A_tab, z, emb, h);

    // graph structure
    deg_hist<<<(NE + 255) / 256, 256, 0, stream>>>(dst, deg);
    const int NB = (NN + 255) / 256;   // 79
    scan_a<<<NB, 256, 0, stream>>>(deg, row_ptr, bsum);
    scan_b<<<NB, 256, 0, stream>>>(bsum, row_ptr, cursor);
    csr_fill<<<(NE + 255) / 256, 256, 0, stream>>>(pos, src, dst, cursor, csr);

    // filter tables + layer-0 xfb
    const int gt32 = (Mt + 31) / 32;
    gemm_t<GDIM><<<dim3(gt32, LAYERS), 256, 0, stream>>>(
        A_tab, mlp_w1, mlp_b1, T1all, Mt, 1, 0, GDIM * 128, 128, Mt * 128);
    gemm_cs2<<<dim3(NN / 32, LAYERS + 1), 256, 0, stream>>>(
        T1all, mlp_w2t, mlp_b2, T, Mt,
        h, conv_w1t, xfb, NN);
    tquant<<<(LAYERS * (TBL + 1) * 128 + 255) / 256, 256, 0, stream>>>(T, Tb);

    const int gn = NN / 16;   // 1250, exact
    for (int l = 0; l < LAYERS; l++) {
        edge_agg<<<NN / 2, 256, 0, stream>>>(row_ptr, csr,
                                             Tb + (size_t)l * (TBL + 1) * 128,
                                             xfb, agg);
        const unsigned short* w1n = (l + 1 < LAYERS) ? conv_w1t + (size_t)(l + 1) * 16384 : nullptr;
        gemm3<<<gn, 256, 0, stream>>>(agg, conv_w2t + (size_t)l * 16384, conv_b2 + l * 128,
                                      lin_wt + (size_t)l * 16384, lin_b + l * 128,
                                      h, h, w1n, xfb);
    }

    // output head (fused): hout = ssp(h @ out1 + b1) @ out2 + b2
    gemm3<<<gn, 256, 0, stream>>>(h, out1_wt, out1_b, out2_wt, out2_b,
                                  nullptr, agg, nullptr, nullptr);

    // per-graph mean
    raccum<<<(NN + RCHUNK - 1) / RCHUNK, 128, 0, stream>>>(agg, batch, out);
    rdiv<<<NGRAPH, 128, 0, stream>>>(batch, out);
}